// Round 9
// baseline (157.987 us; speedup 1.0000x reference)
//
#include <hip/hip_runtime.h>
#include <hip/hip_bf16.h>
#include <math.h>

#define NN 1024
#define LDIM 32
#define HDIM 64

// ---------------- fp32 workspace layout (float offsets) ----------------
#define WS_SELF 0                        // N*L   self_term [i][l]
#define WS_AA   (WS_SELF + NN*LDIM)      // N*H   a_i [i][h]  (pre-scaled by 2log2e)
#define WS_CI   (WS_AA   + NN*HDIM)      // N*L   -log2e*(ci+bc) [i][l]
#define WS_AGG  (WS_CI   + NN*LDIM)      // N     sigmoid(aggr)
#define WS_BI2  (WS_AGG  + NN)           // H     bi2 * 2log2e
#define WS_BI3  (WS_BI2  + HDIM)         // L     bi3 (unscaled)
#define WS_PT   (WS_BI3  + LDIM)         // N*100 partial slab {t1[32],U[32],V[32],sf,pad} (memset 0)
#define WS_FEND (WS_PT   + NN*100)

// ---------------- bf16(u16) region (short offsets from wsu) -------------
#define U_BJB  0                         // N*H   b_j [j][h]  (pre-scaled by 2log2e)
#define U_HJB  (U_BJB + NN*HDIM)         // N*L   h   [j][l]
#define U_JT   (U_HJB + NN*LDIM)         // N*L*4 interleaved {h, -log2e*cj | pc, ps}
#define U_W2B  (U_JT  + NN*LDIM*4)       // H*H   Wi2 [n][k] * 2log2e
#define U_W3B  (U_W2B + HDIM*HDIM)       // L*H   Wi3 [l][k] (unscaled)
#define U_END  (U_W3B + LDIM*HDIM)

// packed-pair transposed weight tables in precompute LDS (uint offsets)
#define PK_W1  0        // 16*64   Ws1
#define PK_W2  1024     // 32*64   Ws2
#define PK_W3  3072     // 32*32   Ws3
#define PK_WI1 4096     // 64*64   Wi1
#define PK_WC  8192     // 32*32   Wc
#define PK_END 9216     // 36 KB

#define K2P  2.88539008f     // 2*log2(e)
#define K1N  (-1.44269504f)  // -log2(e)

typedef __attribute__((ext_vector_type(8))) short bf16x8;
typedef __attribute__((ext_vector_type(4))) float f32x4;

__device__ __forceinline__ float fast_rcp(float x) { return __builtin_amdgcn_rcpf(x); }
__device__ __forceinline__ float fast_tanh(float x) {          // full version (precompute)
    float e = __builtin_amdgcn_exp2f(x * K2P);
    return 1.0f - 2.0f * fast_rcp(e + 1.0f);
}
__device__ __forceinline__ float tanh_pre(float xp) {          // input pre-scaled by 2log2e
    return 1.0f - 2.0f * fast_rcp(__builtin_amdgcn_exp2f(xp) + 1.0f);
}
__device__ __forceinline__ float fast_sigmoid(float x) {       // full version (precompute)
    return fast_rcp(1.0f + __builtin_amdgcn_exp2f(x * K1N));
}
__device__ __forceinline__ float blo(unsigned int u) { union { unsigned int i; float f; } v; v.i = u << 16; return v.f; }
__device__ __forceinline__ float bhi(unsigned int u) { union { unsigned int i; float f; } v; v.i = u & 0xffff0000u; return v.f; }
__device__ __forceinline__ float bf2f(unsigned short u) { union { unsigned int i; float f; } v; v.i = ((unsigned int)u) << 16; return v.f; }
__device__ __forceinline__ unsigned short f2bf(float f) {
    __hip_bfloat16 b = __float2bfloat16(f);
    unsigned short u; __builtin_memcpy(&u, &b, 2); return u;
}
__device__ __forceinline__ unsigned int pk2(float a, float b) {
    float2 t; t.x = a; t.y = b;
    __hip_bfloat162 h = __float22bfloat162_rn(t);
    unsigned int u; __builtin_memcpy(&u, &h, 4); return u;
}

// ------------- kernel 1: precompute (weights packed in-block) -------------
__global__ __launch_bounds__(256) void precompute(
    const float* __restrict__ state,
    const float* __restrict__ Ws1, const float* __restrict__ bs1,
    const float* __restrict__ Ws2, const float* __restrict__ bs2,
    const float* __restrict__ Ws3, const float* __restrict__ bs3,
    const float* __restrict__ Wi1, const float* __restrict__ bi1,
    const float* __restrict__ Wi2, const float* __restrict__ bi2,
    const float* __restrict__ Wi3, const float* __restrict__ bi3,
    const float* __restrict__ phw, const float* __restrict__ Wc,
    const float* __restrict__ bc,  const float* __restrict__ aggr,
    float* __restrict__ ws, unsigned short* __restrict__ wsu) {
    const int tid = threadIdx.x;
    const int w = tid >> 6, t = tid & 63;
    const int i = blockIdx.x * 4 + w;

    __shared__ unsigned int wlds[PK_END];
    __shared__ float shh[4][32], shdh[4][32], sht1[4][64], sht2[4][64];
    __shared__ float shph[4];

    {
        const float2* s1 = (const float2*)Ws1;
        #pragma unroll
        for (int r = 0; r < 4; r++) { int e = tid + r * 256; int f = e >> 4, k2 = e & 15;
            float2 v = s1[e]; wlds[PK_W1 + k2 * 64 + f] = pk2(v.x, v.y); }
        const float2* s2 = (const float2*)Ws2;
        #pragma unroll
        for (int r = 0; r < 8; r++) { int e = tid + r * 256; int f = e >> 5, k2 = e & 31;
            float2 v = s2[e]; wlds[PK_W2 + k2 * 64 + f] = pk2(v.x, v.y); }
        const float2* s3 = (const float2*)Ws3;
        #pragma unroll
        for (int r = 0; r < 4; r++) { int e = tid + r * 256; int f = e >> 5, k2 = e & 31;
            float2 v = s3[e]; wlds[PK_W3 + k2 * 32 + f] = pk2(v.x, v.y); }
        const float2* si = (const float2*)Wi1;
        #pragma unroll
        for (int r = 0; r < 16; r++) { int e = tid + r * 256; int f = e >> 6, c2 = e & 63;
            float2 v = si[e]; wlds[PK_WI1 + c2 * 64 + f] = pk2(v.x, v.y); }
        const float2* sc = (const float2*)Wc;
        #pragma unroll
        for (int r = 0; r < 4; r++) { int e = tid + r * 256; int f = e >> 5, c2 = e & 31;
            float2 v = sc[e]; wlds[PK_WC + c2 * 32 + f] = pk2(v.x, v.y); }
    }
    if (blockIdx.x == 0) {
        #pragma unroll
        for (int r = 0; r < 16; r++) { int e = tid + r * 256; wsu[U_W2B + e] = f2bf(Wi2[e] * K2P); }
        #pragma unroll
        for (int r = 0; r < 8; r++)  { int e = tid + r * 256; wsu[U_W3B + e] = f2bf(Wi3[e]); }
        if (tid < HDIM) ws[WS_BI2 + tid] = bi2[tid] * K2P;
        if (tid < LDIM) ws[WS_BI3 + tid] = bi3[tid];
    }

    float sv = (t < 33) ? state[i * 33 + t] : 0.f;
    if (t < 32) shh[w][t] = sv;
    if (t == 32) shph[w] = sv;
    if (t == 33) ws[WS_AGG + i] = fast_sigmoid(aggr[i]);
    __syncthreads();

    {
        float s = bs1[t];
        const unsigned int* W = wlds + PK_W1;
        #pragma unroll
        for (int k2 = 0; k2 < 16; k2++) {
            unsigned int p = W[k2 * 64 + t];
            s = fmaf(blo(p), shh[w][2 * k2], s);
            s = fmaf(bhi(p), shh[w][2 * k2 + 1], s);
        }
        sht1[w][t] = fast_tanh(s);
    }
    __syncthreads();
    {
        float s = bs2[t];
        const unsigned int* W = wlds + PK_W2;
        #pragma unroll
        for (int k2 = 0; k2 < 32; k2++) {
            unsigned int p = W[k2 * 64 + t];
            s = fmaf(blo(p), sht1[w][2 * k2], s);
            s = fmaf(bhi(p), sht1[w][2 * k2 + 1], s);
        }
        sht2[w][t] = fast_tanh(s);
    }
    __syncthreads();
    if (t < 32) {
        float s = bs3[t];
        const unsigned int* W = wlds + PK_W3;
        #pragma unroll
        for (int k2 = 0; k2 < 32; k2++) {
            unsigned int p = W[k2 * 32 + t];
            s = fmaf(blo(p), sht2[w][2 * k2], s);
            s = fmaf(bhi(p), sht2[w][2 * k2 + 1], s);
        }
        ws[WS_SELF + i * 32 + t] = s;
        shdh[w][t] = s;
    }
    __syncthreads();
    {
        float sa = 0.f, sb = bi1[t];
        const unsigned int* W = wlds + PK_WI1;
        #pragma unroll
        for (int k2 = 0; k2 < 16; k2++) {
            float h0 = shh[w][2 * k2], h1 = shh[w][2 * k2 + 1];
            float d0 = shdh[w][2 * k2], d1 = shdh[w][2 * k2 + 1];
            unsigned int wa  = W[k2 * 64 + t];
            unsigned int wb  = W[(16 + k2) * 64 + t];
            unsigned int wa2 = W[(32 + k2) * 64 + t];
            unsigned int wb2 = W[(48 + k2) * 64 + t];
            sa = fmaf(blo(wa), h0, sa);  sa = fmaf(bhi(wa), h1, sa);
            sb = fmaf(blo(wb), h0, sb);  sb = fmaf(bhi(wb), h1, sb);
            sa = fmaf(blo(wa2), d0, sa); sa = fmaf(bhi(wa2), d1, sa);
            sb = fmaf(blo(wb2), d0, sb); sb = fmaf(bhi(wb2), d1, sb);
        }
        ws[WS_AA + i * 64 + t]  = sa * K2P;          // pre-scaled for tanh_pre
        wsu[U_BJB + i * 64 + t] = f2bf(sb * K2P);
    }
    if (t < 32) {
        float si = 0.f, sj = 0.f;
        const unsigned int* W = wlds + PK_WC;
        #pragma unroll
        for (int m2 = 0; m2 < 16; m2++) {
            float h0 = shh[w][2 * m2], h1 = shh[w][2 * m2 + 1];
            unsigned int wi = W[m2 * 32 + t];
            unsigned int wj = W[(16 + m2) * 32 + t];
            si = fmaf(blo(wi), h0, si); si = fmaf(bhi(wi), h1, si);
            sj = fmaf(blo(wj), h0, sj); sj = fmaf(bhi(wj), h1, sj);
        }
        ws[WS_CI + i * 32 + t] = (si + bc[t]) * K1N; // pre-scaled for rcp(1+exp2)
        float h = shh[w][t];
        wsu[U_HJB + i * 32 + t] = f2bf(h);
        float sc, cc;
        __sincosf(shph[w] * phw[t], &sc, &cc);
        uint2 jt; jt.x = pk2(h, sj * K1N); jt.y = pk2(cc, sc);
        *(uint2*)(wsu + U_JT + (i * 32 + t) * 4) = jt;
    }
}

// ------------- kernel 2: MFMA pairwise core (grid NN x 2, j split) --------
// 8 blocks/CU resident (LDS 20240 B, VGPR target <=128). Single x2 buffer
// with preserved deferral: stage B for tile T-1 READS the buffer at body
// top; the epilogue overwrites it at body bottom (DS ops are in-order per
// wave -> no hazard, full-body RAW distance kept). Wi3 fragments in VGPRs.
// Blocks atomically accumulate linear partials into ws[WS_PT].
__global__ __launch_bounds__(256) void pair_kernel(
    const float* __restrict__ ws, const unsigned short* __restrict__ wsu,
    float* __restrict__ wsmut) {
    const int i    = blockIdx.x;
    const int j0   = blockIdx.y << 9;      // 0 or 512
    const int tid  = threadIdx.x;
    const int w    = tid >> 6;
    const int lane = tid & 63;
    const int q    = lane >> 4;
    const int m    = lane & 15;
    const int jw   = w * 16;
    const int sub  = lane & 3;

    __shared__ unsigned short W2ls[64 * 72];       // 9216 B
    __shared__ unsigned short x2ls[4 * 16 * 72];   // 9216 B (single buffer)
    __shared__ float aLS[64];                      // 256 B
    __shared__ float redT[4][32], redU[4][32], redV[4][32];  // 1536 B
    __shared__ float sfw[4];                       // 16 B

    // ---- setup ----
    if (tid < 64) aLS[tid] = ws[WS_AA + i * 64 + tid];
    {
        int row = tid >> 2, c = (tid & 3) * 16;
        const uint4* s2 = (const uint4*)(wsu + U_W2B + row * 64 + c);
        uint4 d0 = s2[0], d1 = s2[1];
        uint4* dd = (uint4*)(&W2ls[row * 72 + c]);
        dd[0] = d0; dd[1] = d1;
    }
    float hi8[8];
    {
        uint4 hv4 = *(const uint4*)(wsu + U_HJB + i * 32 + sub * 8);
        unsigned int hd[4] = {hv4.x, hv4.y, hv4.z, hv4.w};
        #pragma unroll
        for (int e = 0; e < 4; e++) { hi8[2 * e] = blo(hd[e]); hi8[2 * e + 1] = bhi(hd[e]); }
    }
    f32x4 b2q[4];              // pre-scaled bias slice for MFMA C-init
    #pragma unroll
    for (int nb = 0; nb < 4; nb++) {
        float4 bv = *(const float4*)(ws + WS_BI2 + nb * 16 + q * 4);
        b2q[nb][0] = bv.x; b2q[nb][1] = bv.y; b2q[nb][2] = bv.z; b2q[nb][3] = bv.w;
    }
    bf16x8 w3f[2][2];          // Wi3 fragments in regs (LDS diet for 8 blk/CU)
    #pragma unroll
    for (int lb = 0; lb < 2; lb++)
        #pragma unroll
        for (int s = 0; s < 2; s++)
            w3f[lb][s] = *(const bf16x8*)(wsu + U_W3B + (lb * 16 + m) * 64 + s * 32 + q * 8);
    float hiv[2], cibv[2];
    #pragma unroll
    for (int lb = 0; lb < 2; lb++) {
        int l = lb * 16 + m;
        hiv[lb]  = bf2f(wsu[U_HJB + i * 32 + l]);
        cibv[lb] = ws[WS_CI + i * 32 + l];
    }
    const float aggi = ws[WS_AGG + i];
    const float sub0 = (sub == 0) ? 1.0f : 0.0f;

    // ---- streaming pointers ----
    const unsigned short* hp = wsu + U_HJB + (j0 + jw + (lane >> 2)) * 32 + sub * 8;
    const unsigned short* bp = wsu + U_BJB + (j0 + jw + m) * 64 + q * 8;
    const unsigned short* jp = wsu + U_JT + ((j0 + jw + q * 4) * 32 + m) * 4;
    __syncthreads();

    // persistent accumulators
    f32x4 accK[2];
    #pragma unroll
    for (int lb = 0; lb < 2; lb++) { accK[lb][0]=0.f; accK[lb][1]=0.f; accK[lb][2]=0.f; accK[lb][3]=0.f; }
    float aU[2] = {0.f, 0.f}, aV[2] = {0.f, 0.f};
    float sumfac = 0.f;

    unsigned short* xw = &x2ls[w * 1152];

    #pragma unroll 1
    for (int T = 0; T < 8; T++) {
        // current-tile loads (L2-hit latency hidden by 8 waves/SIMD + stageB)
        uint4 hv = *(const uint4*)hp;  hp += 2048;
        uint4 b0 = *(const uint4*)bp;
        uint4 b1 = *(const uint4*)(bp + 32);  bp += 4096;
        uint2 jt[8];
        #pragma unroll
        for (int r = 0; r < 4; r++) {
            jt[r]     = *(const uint2*)(jp + r * 128);
            jt[4 + r] = *(const uint2*)(jp + 64 + r * 128);
        }
        jp += 8192;

        // deferred stage B for tile T-1: READ xw before this tile overwrites
        if (T > 0) {
            bf16x8 x2f[2];
            #pragma unroll
            for (int s = 0; s < 2; s++)
                x2f[s] = *(const bf16x8*)(&xw[m * 72 + s * 32 + q * 8]);
            #pragma unroll
            for (int lb = 0; lb < 2; lb++) {
                #pragma unroll
                for (int s = 0; s < 2; s++)
                    accK[lb] = __builtin_amdgcn_mfma_f32_16x16x32_bf16(x2f[s], w3f[lb][s], accK[lb], 0, 0, 0);
            }
        }

        // 1) fac (lane owns j = j0 + T*64 + jw + (lane>>2)); zeroed at j==i
        float facm;
        {
            unsigned int hd[4] = {hv.x, hv.y, hv.z, hv.w};
            float s = 0.f;
            #pragma unroll
            for (int e = 0; e < 4; e++) {
                float d0 = hi8[2 * e]     - blo(hd[e]);
                float d1 = hi8[2 * e + 1] - bhi(hd[e]);
                s = fmaf(d0, d0, s); s = fmaf(d1, d1, s);
            }
            s += __shfl_xor(s, 1); s += __shfl_xor(s, 2);
            int jj = j0 + T * 64 + jw + (lane >> 2);
            float facown = fminf(__builtin_amdgcn_rsqf(s), 2.0f) * aggi;
            facown = (jj == i) ? 0.0f : facown;
            sumfac = fmaf(sub0, facown, sumfac);
            facm = __shfl(facown, 4 * m);
        }
        const float fm2 = -2.0f * facm;

        // 2) x1 B-fragments: tanh via pre-scaled inputs
        bf16x8 afr[2];
        {
            unsigned int bd[8] = {b0.x, b0.y, b0.z, b0.w, b1.x, b1.y, b1.z, b1.w};
            #pragma unroll
            for (int s = 0; s < 2; s++) {
                union { uint4 u4; bf16x8 v; } pkd;
                #pragma unroll
                for (int e = 0; e < 4; e++) {
                    const float* ab = &aLS[s * 32 + q * 8 + 2 * e];
                    float x0 = tanh_pre(ab[0] + blo(bd[s * 4 + e]));
                    float x1 = tanh_pre(ab[1] + bhi(bd[s * 4 + e]));
                    ((unsigned int*)&pkd.u4)[e] = pk2(x0, x1);
                }
                afr[s] = pkd.v;
            }
        }

        // 3) stage A: X2^T = Wi2' * X1^T, C-init = scaled bias
        f32x4 accA[4];
        #pragma unroll
        for (int nb = 0; nb < 4; nb++) {
            f32x4 acc = b2q[nb];
            #pragma unroll
            for (int s = 0; s < 2; s++) {
                bf16x8 w2f = *(const bf16x8*)(&W2ls[(nb * 16 + m) * 72 + s * 32 + q * 8]);
                acc = __builtin_amdgcn_mfma_f32_16x16x32_bf16(w2f, afr[s], acc, 0, 0, 0);
            }
            accA[nb] = acc;
        }
        // epilogue A: x2s = fma(-2fac, rcp(exp2(acc)+1), fac) -> xw (overwrite)
        #pragma unroll
        for (int nb = 0; nb < 4; nb++) {
            float r0 = fast_rcp(__builtin_amdgcn_exp2f(accA[nb][0]) + 1.0f);
            float r1 = fast_rcp(__builtin_amdgcn_exp2f(accA[nb][1]) + 1.0f);
            float r2 = fast_rcp(__builtin_amdgcn_exp2f(accA[nb][2]) + 1.0f);
            float r3 = fast_rcp(__builtin_amdgcn_exp2f(accA[nb][3]) + 1.0f);
            float t0 = fmaf(fm2, r0, facm), t1 = fmaf(fm2, r1, facm);
            float t2 = fmaf(fm2, r2, facm), t3 = fmaf(fm2, r3, facm);
            uint2 pk; pk.x = pk2(t0, t1); pk.y = pk2(t2, t3);
            *(uint2*)(&xw[m * 72 + nb * 16 + q * 4]) = pk;
        }

        // 5) stage C: quantum-term partials
        #pragma unroll
        for (int lb = 0; lb < 2; lb++) {
            float u = 0.f, v = 0.f;
            #pragma unroll
            for (int r = 0; r < 4; r++) {
                uint2 jv = jt[lb * 4 + r];
                float hj = blo(jv.x), cj = bhi(jv.x);
                float pjc = blo(jv.y), pjs = bhi(jv.y);
                float coh = fast_rcp(1.0f + __builtin_amdgcn_exp2f(cibv[lb] + cj));
                float cd  = coh * (hiv[lb] - hj);
                u = fmaf(cd, pjc, u);
                v = fmaf(cd, pjs, v);
            }
            aU[lb] += u; aV[lb] += v;
        }
    }
    // stage B for the final tile
    {
        bf16x8 x2f[2];
        #pragma unroll
        for (int s = 0; s < 2; s++)
            x2f[s] = *(const bf16x8*)(&xw[m * 72 + s * 32 + q * 8]);
        #pragma unroll
        for (int lb = 0; lb < 2; lb++) {
            #pragma unroll
            for (int s = 0; s < 2; s++)
                accK[lb] = __builtin_amdgcn_mfma_f32_16x16x32_bf16(x2f[s], w3f[lb][s], accK[lb], 0, 0, 0);
        }
    }

    // ---- block-level reductions + atomic partial accumulation ----
    float T1[2];
    #pragma unroll
    for (int lb = 0; lb < 2; lb++) {
        T1[lb] = (accK[lb][0] + accK[lb][1]) + (accK[lb][2] + accK[lb][3]);
        T1[lb] += __shfl_xor(T1[lb], 16); T1[lb] += __shfl_xor(T1[lb], 32);
        aU[lb] += __shfl_xor(aU[lb], 16); aU[lb] += __shfl_xor(aU[lb], 32);
        aV[lb] += __shfl_xor(aV[lb], 16); aV[lb] += __shfl_xor(aV[lb], 32);
    }
    sumfac += __shfl_xor(sumfac, 1);  sumfac += __shfl_xor(sumfac, 2);
    sumfac += __shfl_xor(sumfac, 4);  sumfac += __shfl_xor(sumfac, 8);
    sumfac += __shfl_xor(sumfac, 16); sumfac += __shfl_xor(sumfac, 32);
    if (lane < 16) {
        redT[w][m] = T1[0];      redT[w][16 + m] = T1[1];
        redU[w][m] = aU[0];      redU[w][16 + m] = aU[1];
        redV[w][m] = aV[0];      redV[w][16 + m] = aV[1];
    }
    if (lane == 0) sfw[w] = sumfac;
    __syncthreads();
    float* PT = wsmut + WS_PT + i * 100;
    if (tid < 32) {
        int l = tid;
        atomicAdd(&PT[l],      (redT[0][l] + redT[1][l]) + (redT[2][l] + redT[3][l]));
        atomicAdd(&PT[32 + l], (redU[0][l] + redU[1][l]) + (redU[2][l] + redU[3][l]));
        atomicAdd(&PT[64 + l], (redV[0][l] + redV[1][l]) + (redV[2][l] + redV[3][l]));
    }
    if (tid == 0) atomicAdd(&PT[96], (sfw[0] + sfw[1]) + (sfw[2] + sfw[3]));
}

// ------------- kernel 3: finalize (1024 x 64) -----------------------------
__global__ __launch_bounds__(64) void finalize(
    const float* __restrict__ ws, const unsigned short* __restrict__ wsu,
    float* __restrict__ out) {
    const int i = blockIdx.x, t = threadIdx.x;
    float a = 0.f;
    if (t < 32) {
        const float* PT = ws + WS_PT + i * 100;
        float t1 = PT[t], uu = PT[32 + t], vv = PT[64 + t], sf = PT[96];
        uint2 jti = *(const uint2*)(wsu + U_JT + (i * 32 + t) * 4);
        float pic = blo(jti.y), pis = bhi(jti.y);
        float isum = t1 + sf * ws[WS_BI3 + t] - (pic * uu + pis * vv);
        out[i * 33 + t] = 0.5f * ws[WS_SELF + i * 32 + t] + 0.3f * isum;
        a = fabsf(isum);
    }
    a += __shfl_xor(a, 1);  a += __shfl_xor(a, 2);  a += __shfl_xor(a, 4);
    a += __shfl_xor(a, 8);  a += __shfl_xor(a, 16); a += __shfl_xor(a, 32);
    if (t == 0) out[i * 33 + 32] = 0.1f + 0.05f * a;
}

extern "C" void kernel_launch(void* const* d_in, const int* in_sizes, int n_in,
                              void* d_out, int out_size, void* d_ws, size_t ws_size,
                              hipStream_t stream) {
    const float* state   = (const float*)d_in[0];
    const float* Ws1     = (const float*)d_in[1];
    const float* bs1     = (const float*)d_in[2];
    const float* Ws2     = (const float*)d_in[3];
    const float* bs2     = (const float*)d_in[4];
    const float* Ws3     = (const float*)d_in[5];
    const float* bs3     = (const float*)d_in[6];
    const float* Wi1     = (const float*)d_in[7];
    const float* bi1     = (const float*)d_in[8];
    const float* Wi2     = (const float*)d_in[9];
    const float* bi2     = (const float*)d_in[10];
    const float* Wi3     = (const float*)d_in[11];
    const float* bi3     = (const float*)d_in[12];
    const float* phase_w = (const float*)d_in[13];
    const float* Wc      = (const float*)d_in[14];
    const float* bc      = (const float*)d_in[15];
    const float* aggr    = (const float*)d_in[16];

    float* ws = (float*)d_ws;
    unsigned short* wsu = (unsigned short*)(ws + WS_FEND);
    float* out = (float*)d_out;

    // zero the cross-block partial slab (d_ws is poisoned before each call)
    hipMemsetAsync(ws + WS_PT, 0, NN * 100 * sizeof(float), stream);

    precompute<<<256, 256, 0, stream>>>(state, Ws1, bs1, Ws2, bs2, Ws3, bs3,
                                        Wi1, bi1, Wi2, bi2, Wi3, bi3,
                                        phase_w, Wc, bc, aggr, ws, wsu);
    pair_kernel<<<dim3(NN, 2), 256, 0, stream>>>(ws, wsu, ws);
    finalize<<<NN, 64, 0, stream>>>(ws, wsu, out);
}

// Round 10
// 156.911 us; speedup vs baseline: 1.0069x; 1.0069x over previous
//
#include <hip/hip_runtime.h>
#include <hip/hip_bf16.h>
#include <math.h>

#define NN 1024
#define LDIM 32
#define HDIM 64

// ---------------- fp32 workspace layout (float offsets) ----------------
#define WS_SELF 0                        // N*L   self_term [i][l]
#define WS_AA   (WS_SELF + NN*LDIM)      // N*H   a_i [i][h]  (pre-scaled by 2log2e)
#define WS_CI   (WS_AA   + NN*HDIM)      // N*L   -log2e*(ci+bc) [i][l]
#define WS_AGG  (WS_CI   + NN*LDIM)      // N     sigmoid(aggr)
#define WS_BI2  (WS_AGG  + NN)           // H     bi2 * 2log2e
#define WS_BI3  (WS_BI2  + HDIM)         // L     bi3 (unscaled)
#define WS_FEND (WS_BI3  + LDIM)

// ---------------- bf16(u16) region (short offsets from wsu) -------------
#define U_BJB  0                         // N*H   b_j [j][h]  (pre-scaled by 2log2e)
#define U_HJB  (U_BJB + NN*HDIM)         // N*L   h   [j][l]
#define U_JT   (U_HJB + NN*LDIM)         // N*L*4 interleaved {h, -log2e*cj | pc, ps}
#define U_W2B  (U_JT  + NN*LDIM*4)       // H*H   Wi2 [n][k] * 2log2e
#define U_W3B  (U_W2B + HDIM*HDIM)       // L*H   Wi3 [l][k] (unscaled)
#define U_FAC  (U_W3B + LDIM*HDIM)       // N*N   fac[i][j] bf16 (0 at j==i)
#define U_END  (U_FAC + NN*NN)

// packed-pair transposed weight tables in precompute LDS (uint offsets)
#define PK_W1  0        // 16*64   Ws1
#define PK_W2  1024     // 32*64   Ws2
#define PK_W3  3072     // 32*32   Ws3
#define PK_WI1 4096     // 64*64   Wi1
#define PK_WC  8192     // 32*32   Wc
#define PK_END 9216     // 36 KB

#define K2P  2.88539008f     // 2*log2(e)
#define K1N  (-1.44269504f)  // -log2(e)

typedef __attribute__((ext_vector_type(8))) short bf16x8;
typedef __attribute__((ext_vector_type(4))) float f32x4;

__device__ __forceinline__ float fast_rcp(float x) { return __builtin_amdgcn_rcpf(x); }
__device__ __forceinline__ float fast_tanh(float x) {          // full version (precompute)
    float e = __builtin_amdgcn_exp2f(x * K2P);
    return 1.0f - 2.0f * fast_rcp(e + 1.0f);
}
__device__ __forceinline__ float tanh_pre(float xp) {          // input pre-scaled by 2log2e
    return 1.0f - 2.0f * fast_rcp(__builtin_amdgcn_exp2f(xp) + 1.0f);
}
__device__ __forceinline__ float fast_sigmoid(float x) {       // full version (precompute)
    return fast_rcp(1.0f + __builtin_amdgcn_exp2f(x * K1N));
}
__device__ __forceinline__ float blo(unsigned int u) { union { unsigned int i; float f; } v; v.i = u << 16; return v.f; }
__device__ __forceinline__ float bhi(unsigned int u) { union { unsigned int i; float f; } v; v.i = u & 0xffff0000u; return v.f; }
__device__ __forceinline__ float bf2f(unsigned short u) { union { unsigned int i; float f; } v; v.i = ((unsigned int)u) << 16; return v.f; }
__device__ __forceinline__ unsigned short f2bf(float f) {
    __hip_bfloat16 b = __float2bfloat16(f);
    unsigned short u; __builtin_memcpy(&u, &b, 2); return u;
}
__device__ __forceinline__ unsigned int pk2(float a, float b) {
    float2 t; t.x = a; t.y = b;
    __hip_bfloat162 h = __float22bfloat162_rn(t);
    unsigned int u; __builtin_memcpy(&u, &h, 4); return u;
}

// ------------- kernel 1: precompute (weights packed in-block) -------------
__global__ __launch_bounds__(256) void precompute(
    const float* __restrict__ state,
    const float* __restrict__ Ws1, const float* __restrict__ bs1,
    const float* __restrict__ Ws2, const float* __restrict__ bs2,
    const float* __restrict__ Ws3, const float* __restrict__ bs3,
    const float* __restrict__ Wi1, const float* __restrict__ bi1,
    const float* __restrict__ Wi2, const float* __restrict__ bi2,
    const float* __restrict__ Wi3, const float* __restrict__ bi3,
    const float* __restrict__ phw, const float* __restrict__ Wc,
    const float* __restrict__ bc,  const float* __restrict__ aggr,
    float* __restrict__ ws, unsigned short* __restrict__ wsu) {
    const int tid = threadIdx.x;
    const int w = tid >> 6, t = tid & 63;
    const int i = blockIdx.x * 4 + w;

    __shared__ unsigned int wlds[PK_END];
    __shared__ float shh[4][32], shdh[4][32], sht1[4][64], sht2[4][64];
    __shared__ float shph[4];

    {
        const float2* s1 = (const float2*)Ws1;
        #pragma unroll
        for (int r = 0; r < 4; r++) { int e = tid + r * 256; int f = e >> 4, k2 = e & 15;
            float2 v = s1[e]; wlds[PK_W1 + k2 * 64 + f] = pk2(v.x, v.y); }
        const float2* s2 = (const float2*)Ws2;
        #pragma unroll
        for (int r = 0; r < 8; r++) { int e = tid + r * 256; int f = e >> 5, k2 = e & 31;
            float2 v = s2[e]; wlds[PK_W2 + k2 * 64 + f] = pk2(v.x, v.y); }
        const float2* s3 = (const float2*)Ws3;
        #pragma unroll
        for (int r = 0; r < 4; r++) { int e = tid + r * 256; int f = e >> 5, k2 = e & 31;
            float2 v = s3[e]; wlds[PK_W3 + k2 * 32 + f] = pk2(v.x, v.y); }
        const float2* si = (const float2*)Wi1;
        #pragma unroll
        for (int r = 0; r < 16; r++) { int e = tid + r * 256; int f = e >> 6, c2 = e & 63;
            float2 v = si[e]; wlds[PK_WI1 + c2 * 64 + f] = pk2(v.x, v.y); }
        const float2* sc = (const float2*)Wc;
        #pragma unroll
        for (int r = 0; r < 4; r++) { int e = tid + r * 256; int f = e >> 5, c2 = e & 31;
            float2 v = sc[e]; wlds[PK_WC + c2 * 32 + f] = pk2(v.x, v.y); }
    }
    if (blockIdx.x == 0) {
        #pragma unroll
        for (int r = 0; r < 16; r++) { int e = tid + r * 256; wsu[U_W2B + e] = f2bf(Wi2[e] * K2P); }
        #pragma unroll
        for (int r = 0; r < 8; r++)  { int e = tid + r * 256; wsu[U_W3B + e] = f2bf(Wi3[e]); }
        if (tid < HDIM) ws[WS_BI2 + tid] = bi2[tid] * K2P;
        if (tid < LDIM) ws[WS_BI3 + tid] = bi3[tid];
    }

    float sv = (t < 33) ? state[i * 33 + t] : 0.f;
    if (t < 32) shh[w][t] = sv;
    if (t == 32) shph[w] = sv;
    if (t == 33) ws[WS_AGG + i] = fast_sigmoid(aggr[i]);
    __syncthreads();

    {
        float s = bs1[t];
        const unsigned int* W = wlds + PK_W1;
        #pragma unroll
        for (int k2 = 0; k2 < 16; k2++) {
            unsigned int p = W[k2 * 64 + t];
            s = fmaf(blo(p), shh[w][2 * k2], s);
            s = fmaf(bhi(p), shh[w][2 * k2 + 1], s);
        }
        sht1[w][t] = fast_tanh(s);
    }
    __syncthreads();
    {
        float s = bs2[t];
        const unsigned int* W = wlds + PK_W2;
        #pragma unroll
        for (int k2 = 0; k2 < 32; k2++) {
            unsigned int p = W[k2 * 64 + t];
            s = fmaf(blo(p), sht1[w][2 * k2], s);
            s = fmaf(bhi(p), sht1[w][2 * k2 + 1], s);
        }
        sht2[w][t] = fast_tanh(s);
    }
    __syncthreads();
    if (t < 32) {
        float s = bs3[t];
        const unsigned int* W = wlds + PK_W3;
        #pragma unroll
        for (int k2 = 0; k2 < 32; k2++) {
            unsigned int p = W[k2 * 32 + t];
            s = fmaf(blo(p), sht2[w][2 * k2], s);
            s = fmaf(bhi(p), sht2[w][2 * k2 + 1], s);
        }
        ws[WS_SELF + i * 32 + t] = s;
        shdh[w][t] = s;
    }
    __syncthreads();
    {
        float sa = 0.f, sb = bi1[t];
        const unsigned int* W = wlds + PK_WI1;
        #pragma unroll
        for (int k2 = 0; k2 < 16; k2++) {
            float h0 = shh[w][2 * k2], h1 = shh[w][2 * k2 + 1];
            float d0 = shdh[w][2 * k2], d1 = shdh[w][2 * k2 + 1];
            unsigned int wa  = W[k2 * 64 + t];
            unsigned int wb  = W[(16 + k2) * 64 + t];
            unsigned int wa2 = W[(32 + k2) * 64 + t];
            unsigned int wb2 = W[(48 + k2) * 64 + t];
            sa = fmaf(blo(wa), h0, sa);  sa = fmaf(bhi(wa), h1, sa);
            sb = fmaf(blo(wb), h0, sb);  sb = fmaf(bhi(wb), h1, sb);
            sa = fmaf(blo(wa2), d0, sa); sa = fmaf(bhi(wa2), d1, sa);
            sb = fmaf(blo(wb2), d0, sb); sb = fmaf(bhi(wb2), d1, sb);
        }
        ws[WS_AA + i * 64 + t]  = sa * K2P;          // pre-scaled for tanh_pre
        wsu[U_BJB + i * 64 + t] = f2bf(sb * K2P);
    }
    if (t < 32) {
        float si = 0.f, sj = 0.f;
        const unsigned int* W = wlds + PK_WC;
        #pragma unroll
        for (int m2 = 0; m2 < 16; m2++) {
            float h0 = shh[w][2 * m2], h1 = shh[w][2 * m2 + 1];
            unsigned int wi = W[m2 * 32 + t];
            unsigned int wj = W[(16 + m2) * 32 + t];
            si = fmaf(blo(wi), h0, si); si = fmaf(bhi(wi), h1, si);
            sj = fmaf(blo(wj), h0, sj); sj = fmaf(bhi(wj), h1, sj);
        }
        ws[WS_CI + i * 32 + t] = (si + bc[t]) * K1N; // pre-scaled for rcp(1+exp2)
        float h = shh[w][t];
        wsu[U_HJB + i * 32 + t] = f2bf(h);
        float sc, cc;
        __sincosf(shph[w] * phw[t], &sc, &cc);
        uint2 jt; jt.x = pk2(h, sj * K1N); jt.y = pk2(cc, sc);
        *(uint2*)(wsu + U_JT + (i * 32 + t) * 4) = jt;
    }
}

// ------------- kernel 2: fac table. fac[i][j] = min(rsq(d2),2)*agg_i ------
// One block per i, 256 threads x 4 j each; h table (64 KB) is L2-resident.
__global__ __launch_bounds__(256) void fac_kernel(
    const float* __restrict__ ws, unsigned short* __restrict__ wsu) {
    const int i = blockIdx.x, tid = threadIdx.x;
    __shared__ float hi[32];
    __shared__ float ag[1];
    if (tid < 32) hi[tid] = bf2f(wsu[U_HJB + i * 32 + tid]);
    if (tid == 32) ag[0] = ws[WS_AGG + i];
    __syncthreads();
    const float agg = ag[0];
    #pragma unroll
    for (int r = 0; r < 4; r++) {
        int j = tid + r * 256;
        const uint4* hj = (const uint4*)(wsu + U_HJB + j * 32);
        float s = 0.f;
        #pragma unroll
        for (int v4 = 0; v4 < 4; v4++) {
            uint4 hv = hj[v4];
            unsigned int hd[4] = {hv.x, hv.y, hv.z, hv.w};
            #pragma unroll
            for (int e = 0; e < 4; e++) {
                float d0 = hi[v4 * 8 + 2 * e]     - blo(hd[e]);
                float d1 = hi[v4 * 8 + 2 * e + 1] - bhi(hd[e]);
                s = fmaf(d0, d0, s); s = fmaf(d1, d1, s);
            }
        }
        float f = fminf(__builtin_amdgcn_rsqf(s), 2.0f) * agg;
        wsu[U_FAC + i * 1024 + j] = (j == i) ? (unsigned short)0 : f2bf(f);
    }
}

// ------------- kernel 3: MFMA pairwise core (1 block per i) ---------------
// Round-8 structure (best verified) + fac table: the per-tile distance/
// shuffle block is replaced by one 2-byte broadcast load from U_FAC.
__global__ __launch_bounds__(256) void pair_kernel(
    const float* __restrict__ ws, const unsigned short* __restrict__ wsu,
    float* __restrict__ out) {
    const int i    = blockIdx.x;
    const int tid  = threadIdx.x;
    const int w    = tid >> 6;
    const int lane = tid & 63;
    const int q    = lane >> 4;
    const int m    = lane & 15;
    const int jw   = w * 16;

    __shared__ unsigned short W2ls[64 * 72];
    __shared__ unsigned short W3ls[32 * 72];
    __shared__ unsigned short x2ls[4 * 2 * 16 * 72];   // per-wave double buffer
    __shared__ float aLS[64];
    __shared__ float redT[4][32], redU[4][32], redV[4][32];
    __shared__ float sfw[4];

    // ---- setup ----
    if (tid < 64) aLS[tid] = ws[WS_AA + i * 64 + tid];
    {
        int row = tid >> 2, c = (tid & 3) * 16;
        const uint4* s2 = (const uint4*)(wsu + U_W2B + row * 64 + c);
        uint4 d0 = s2[0], d1 = s2[1];
        uint4* dd = (uint4*)(&W2ls[row * 72 + c]);
        dd[0] = d0; dd[1] = d1;
        if (row < 32) {
            const uint4* s3 = (const uint4*)(wsu + U_W3B + row * 64 + c);
            uint4 e0 = s3[0], e1 = s3[1];
            uint4* d3 = (uint4*)(&W3ls[row * 72 + c]);
            d3[0] = e0; d3[1] = e1;
        }
    }
    f32x4 b2q[4];              // pre-scaled bias slice for MFMA C-init
    #pragma unroll
    for (int nb = 0; nb < 4; nb++) {
        float4 bv = *(const float4*)(ws + WS_BI2 + nb * 16 + q * 4);
        b2q[nb][0] = bv.x; b2q[nb][1] = bv.y; b2q[nb][2] = bv.z; b2q[nb][3] = bv.w;
    }
    float hiv[2], cibv[2];
    #pragma unroll
    for (int lb = 0; lb < 2; lb++) {
        int l = lb * 16 + m;
        hiv[lb]  = bf2f(wsu[U_HJB + i * 32 + l]);
        cibv[lb] = ws[WS_CI + i * 32 + l];
    }
    const float q0 = (q == 0) ? 1.0f : 0.0f;

    // ---- streaming pointers + tile-0 prefetch ----
    const unsigned short* bp = wsu + U_BJB + (jw + m) * 64 + q * 8;
    const unsigned short* jp = wsu + U_JT + ((jw + q * 4) * 32 + m) * 4;
    const unsigned short* fp = wsu + U_FAC + i * 1024 + jw;

    uint4 b0A = *(const uint4*)bp;
    uint4 b1A = *(const uint4*)(bp + 32);
    uint4 b0B, b1B;
    __syncthreads();

    // persistent accumulators
    f32x4 accK[2];
    #pragma unroll
    for (int lb = 0; lb < 2; lb++) { accK[lb][0]=0.f; accK[lb][1]=0.f; accK[lb][2]=0.f; accK[lb][3]=0.f; }
    float aU[2] = {0.f, 0.f}, aV[2] = {0.f, 0.f};
    float sumfac = 0.f;

    unsigned short* xb0 = &x2ls[w * 2 * 1152];
    unsigned short* xb1 = xb0 + 1152;

    auto stageB = [&](const unsigned short* xb) {
        bf16x8 x2f[2];
        #pragma unroll
        for (int s = 0; s < 2; s++)
            x2f[s] = *(const bf16x8*)(&xb[m * 72 + s * 32 + q * 8]);
        #pragma unroll
        for (int lb = 0; lb < 2; lb++) {
            #pragma unroll
            for (int s = 0; s < 2; s++) {
                bf16x8 w3f = *(const bf16x8*)(&W3ls[(lb * 16 + m) * 72 + s * 32 + q * 8]);
                accK[lb] = __builtin_amdgcn_mfma_f32_16x16x32_bf16(x2f[s], w3f, accK[lb], 0, 0, 0);
            }
        }
    };

    auto body = [&](int T, uint4 b0c, uint4 b1c,
                    uint4& b0n, uint4& b1n,
                    unsigned short* xcur, const unsigned short* xprev) {
        // prefetch next tile's b
        bp += 4096;
        b0n = *(const uint4*)bp;
        b1n = *(const uint4*)(bp + 32);
        // fac for this lane's column (broadcast across q) + jt loads
        float facm = bf2f(fp[m]);  fp += 64;
        uint2 jt[8];
        #pragma unroll
        for (int r = 0; r < 4; r++) {
            jt[r]     = *(const uint2*)(jp + r * 128);
            jt[4 + r] = *(const uint2*)(jp + 64 + r * 128);
        }
        jp += 8192;

        // deferred stage B for previous tile (LDS data a full body old)
        if (T > 0) stageB(xprev);

        sumfac = fmaf(q0, facm, sumfac);
        const float fm2 = -2.0f * facm;

        // 2) x1 B-fragments: tanh via pre-scaled inputs
        bf16x8 afr[2];
        {
            unsigned int bd[8] = {b0c.x, b0c.y, b0c.z, b0c.w, b1c.x, b1c.y, b1c.z, b1c.w};
            #pragma unroll
            for (int s = 0; s < 2; s++) {
                union { uint4 u4; bf16x8 v; } pkd;
                #pragma unroll
                for (int e = 0; e < 4; e++) {
                    const float* ab = &aLS[s * 32 + q * 8 + 2 * e];
                    float x0 = tanh_pre(ab[0] + blo(bd[s * 4 + e]));
                    float x1 = tanh_pre(ab[1] + bhi(bd[s * 4 + e]));
                    ((unsigned int*)&pkd.u4)[e] = pk2(x0, x1);
                }
                afr[s] = pkd.v;
            }
        }

        // 3) stage A: X2^T = Wi2' * X1^T, C-init = scaled bias
        f32x4 accA[4];
        #pragma unroll
        for (int nb = 0; nb < 4; nb++) {
            f32x4 acc = b2q[nb];
            #pragma unroll
            for (int s = 0; s < 2; s++) {
                bf16x8 w2f = *(const bf16x8*)(&W2ls[(nb * 16 + m) * 72 + s * 32 + q * 8]);
                acc = __builtin_amdgcn_mfma_f32_16x16x32_bf16(w2f, afr[s], acc, 0, 0, 0);
            }
            accA[nb] = acc;
        }
        // epilogue A: x2s = fma(-2fac, rcp(exp2(acc)+1), fac)
        #pragma unroll
        for (int nb = 0; nb < 4; nb++) {
            float r0 = fast_rcp(__builtin_amdgcn_exp2f(accA[nb][0]) + 1.0f);
            float r1 = fast_rcp(__builtin_amdgcn_exp2f(accA[nb][1]) + 1.0f);
            float r2 = fast_rcp(__builtin_amdgcn_exp2f(accA[nb][2]) + 1.0f);
            float r3 = fast_rcp(__builtin_amdgcn_exp2f(accA[nb][3]) + 1.0f);
            float t0 = fmaf(fm2, r0, facm), t1 = fmaf(fm2, r1, facm);
            float t2 = fmaf(fm2, r2, facm), t3 = fmaf(fm2, r3, facm);
            uint2 pk; pk.x = pk2(t0, t1); pk.y = pk2(t2, t3);
            *(uint2*)(&xcur[m * 72 + nb * 16 + q * 4]) = pk;
        }

        // 5) stage C: quantum-term partials
        #pragma unroll
        for (int lb = 0; lb < 2; lb++) {
            float u = 0.f, v = 0.f;
            #pragma unroll
            for (int r = 0; r < 4; r++) {
                uint2 jv = jt[lb * 4 + r];
                float hj = blo(jv.x), cj = bhi(jv.x);
                float pjc = blo(jv.y), pjs = bhi(jv.y);
                float coh = fast_rcp(1.0f + __builtin_amdgcn_exp2f(cibv[lb] + cj));
                float cd  = coh * (hiv[lb] - hj);
                u = fmaf(cd, pjc, u);
                v = fmaf(cd, pjs, v);
            }
            aU[lb] += u; aV[lb] += v;
        }
    };

    #pragma unroll 1
    for (int T = 0; T < 16; T += 2) {
        body(T,     b0A, b1A, b0B, b1B, xb0, xb1);
        body(T + 1, b0B, b1B, b0A, b1A, xb1, xb0);
    }
    stageB(xb1);   // tile 15

    // ---- final reductions ----
    float T1[2];
    #pragma unroll
    for (int lb = 0; lb < 2; lb++) {
        T1[lb] = (accK[lb][0] + accK[lb][1]) + (accK[lb][2] + accK[lb][3]);
        T1[lb] += __shfl_xor(T1[lb], 16); T1[lb] += __shfl_xor(T1[lb], 32);
        aU[lb] += __shfl_xor(aU[lb], 16); aU[lb] += __shfl_xor(aU[lb], 32);
        aV[lb] += __shfl_xor(aV[lb], 16); aV[lb] += __shfl_xor(aV[lb], 32);
    }
    sumfac += __shfl_xor(sumfac, 1);  sumfac += __shfl_xor(sumfac, 2);
    sumfac += __shfl_xor(sumfac, 4);  sumfac += __shfl_xor(sumfac, 8);
    sumfac += __shfl_xor(sumfac, 16); sumfac += __shfl_xor(sumfac, 32);
    if (lane < 16) {
        redT[w][m] = T1[0];      redT[w][16 + m] = T1[1];
        redU[w][m] = aU[0];      redU[w][16 + m] = aU[1];
        redV[w][m] = aV[0];      redV[w][16 + m] = aV[1];
    }
    if (lane == 0) sfw[w] = sumfac;
    __syncthreads();
    if (tid < 32) {
        int l = tid;
        float t1 = (redT[0][l] + redT[1][l]) + (redT[2][l] + redT[3][l]);
        float uu = (redU[0][l] + redU[1][l]) + (redU[2][l] + redU[3][l]);
        float vv = (redV[0][l] + redV[1][l]) + (redV[2][l] + redV[3][l]);
        float sf = (sfw[0] + sfw[1]) + (sfw[2] + sfw[3]);
        uint2 jti = *(const uint2*)(wsu + U_JT + (i * 32 + l) * 4);
        float pic = blo(jti.y), pis = bhi(jti.y);
        float isum = t1 + sf * ws[WS_BI3 + l] - (pic * uu + pis * vv);
        out[i * 33 + l] = 0.5f * ws[WS_SELF + i * 32 + l] + 0.3f * isum;
        redT[0][l] = fabsf(isum);
    }
    __syncthreads();
    if (tid == 0) {
        float s = 0.f;
        #pragma unroll
        for (int l = 0; l < 32; l++) s += redT[0][l];
        out[i * 33 + 32] = 0.1f + 0.05f * s;
    }
}

extern "C" void kernel_launch(void* const* d_in, const int* in_sizes, int n_in,
                              void* d_out, int out_size, void* d_ws, size_t ws_size,
                              hipStream_t stream) {
    const float* state   = (const float*)d_in[0];
    const float* Ws1     = (const float*)d_in[1];
    const float* bs1     = (const float*)d_in[2];
    const float* Ws2     = (const float*)d_in[3];
    const float* bs2     = (const float*)d_in[4];
    const float* Ws3     = (const float*)d_in[5];
    const float* bs3     = (const float*)d_in[6];
    const float* Wi1     = (const float*)d_in[7];
    const float* bi1     = (const float*)d_in[8];
    const float* Wi2     = (const float*)d_in[9];
    const float* bi2     = (const float*)d_in[10];
    const float* Wi3     = (const float*)d_in[11];
    const float* bi3     = (const float*)d_in[12];
    const float* phase_w = (const float*)d_in[13];
    const float* Wc      = (const float*)d_in[14];
    const float* bc      = (const float*)d_in[15];
    const float* aggr    = (const float*)d_in[16];

    float* ws = (float*)d_ws;
    unsigned short* wsu = (unsigned short*)(ws + WS_FEND);
    float* out = (float*)d_out;

    precompute<<<256, 256, 0, stream>>>(state, Ws1, bs1, Ws2, bs2, Ws3, bs3,
                                        Wi1, bi1, Wi2, bi2, Wi3, bi3,
                                        phase_w, Wc, bc, aggr, ws, wsu);
    fac_kernel<<<NN, 256, 0, stream>>>(ws, wsu);
    pair_kernel<<<NN, 256, 0, stream>>>(ws, wsu, out);
}

// Round 11
// 152.606 us; speedup vs baseline: 1.0353x; 1.0282x over previous
//
#include <hip/hip_runtime.h>
#include <hip/hip_bf16.h>
#include <math.h>

#define NN 1024
#define LDIM 32
#define HDIM 64

// ---------------- fp32 workspace layout (float offsets) ----------------
#define WS_SELF 0                        // N*L   self_term [i][l]
#define WS_AA   (WS_SELF + NN*LDIM)      // N*H   a_i [i][h]  (pre-scaled by 2log2e)
#define WS_CI   (WS_AA   + NN*HDIM)      // N*L   -log2e*(ci+bc) [i][l]
#define WS_AGG  (WS_CI   + NN*LDIM)      // N     sigmoid(aggr)
#define WS_BI2  (WS_AGG  + NN)           // H     bi2 * 2log2e
#define WS_BI3  (WS_BI2  + HDIM)         // L     bi3 (unscaled)
#define WS_FEND (WS_BI3  + LDIM)

// ---------------- bf16(u16) region (short offsets from wsu) -------------
#define U_BJB  0                         // N*H   b_j [j][h]  (pre-scaled by 2log2e)
#define U_HJB  (U_BJB + NN*HDIM)         // N*L   h   [j][l]
#define U_JT   (U_HJB + NN*LDIM)         // N*L*4 interleaved {h, -log2e*cj | pc, ps}
#define U_W2B  (U_JT  + NN*LDIM*4)       // H*H   Wi2 [n][k] * 2log2e
#define U_W3B  (U_W2B + HDIM*HDIM)       // L*H   Wi3 [l][k] (unscaled)
#define U_END  (U_W3B + LDIM*HDIM)

// packed-pair transposed weight tables in precompute LDS (uint offsets)
#define PK_W1  0        // 16*64   Ws1
#define PK_W2  1024     // 32*64   Ws2
#define PK_W3  3072     // 32*32   Ws3
#define PK_WI1 4096     // 64*64   Wi1
#define PK_WC  8192     // 32*32   Wc
#define PK_END 9216     // 36 KB

#define K2P  2.88539008f     // 2*log2(e)
#define K1N  (-1.44269504f)  // -log2(e)

typedef __attribute__((ext_vector_type(8))) short bf16x8;
typedef __attribute__((ext_vector_type(4))) float f32x4;

__device__ __forceinline__ float fast_rcp(float x) { return __builtin_amdgcn_rcpf(x); }
__device__ __forceinline__ float fast_tanh(float x) {          // full version (precompute)
    float e = __builtin_amdgcn_exp2f(x * K2P);
    return 1.0f - 2.0f * fast_rcp(e + 1.0f);
}
__device__ __forceinline__ float tanh_pre(float xp) {          // input pre-scaled by 2log2e
    return 1.0f - 2.0f * fast_rcp(__builtin_amdgcn_exp2f(xp) + 1.0f);
}
__device__ __forceinline__ float fast_sigmoid(float x) {       // full version (precompute)
    return fast_rcp(1.0f + __builtin_amdgcn_exp2f(x * K1N));
}
__device__ __forceinline__ float blo(unsigned int u) { union { unsigned int i; float f; } v; v.i = u << 16; return v.f; }
__device__ __forceinline__ float bhi(unsigned int u) { union { unsigned int i; float f; } v; v.i = u & 0xffff0000u; return v.f; }
__device__ __forceinline__ float bf2f(unsigned short u) { union { unsigned int i; float f; } v; v.i = ((unsigned int)u) << 16; return v.f; }
__device__ __forceinline__ unsigned short f2bf(float f) {
    __hip_bfloat16 b = __float2bfloat16(f);
    unsigned short u; __builtin_memcpy(&u, &b, 2); return u;
}
__device__ __forceinline__ unsigned int pk2(float a, float b) {
    float2 t; t.x = a; t.y = b;
    __hip_bfloat162 h = __float22bfloat162_rn(t);
    unsigned int u; __builtin_memcpy(&u, &h, 4); return u;
}

// ------------- kernel 1: precompute (weights packed in-block) -------------
__global__ __launch_bounds__(256) void precompute(
    const float* __restrict__ state,
    const float* __restrict__ Ws1, const float* __restrict__ bs1,
    const float* __restrict__ Ws2, const float* __restrict__ bs2,
    const float* __restrict__ Ws3, const float* __restrict__ bs3,
    const float* __restrict__ Wi1, const float* __restrict__ bi1,
    const float* __restrict__ Wi2, const float* __restrict__ bi2,
    const float* __restrict__ Wi3, const float* __restrict__ bi3,
    const float* __restrict__ phw, const float* __restrict__ Wc,
    const float* __restrict__ bc,  const float* __restrict__ aggr,
    float* __restrict__ ws, unsigned short* __restrict__ wsu) {
    const int tid = threadIdx.x;
    const int w = tid >> 6, t = tid & 63;
    const int i = blockIdx.x * 4 + w;

    __shared__ unsigned int wlds[PK_END];
    __shared__ float shh[4][32], shdh[4][32], sht1[4][64], sht2[4][64];
    __shared__ float shph[4];

    {
        const float2* s1 = (const float2*)Ws1;
        #pragma unroll
        for (int r = 0; r < 4; r++) { int e = tid + r * 256; int f = e >> 4, k2 = e & 15;
            float2 v = s1[e]; wlds[PK_W1 + k2 * 64 + f] = pk2(v.x, v.y); }
        const float2* s2 = (const float2*)Ws2;
        #pragma unroll
        for (int r = 0; r < 8; r++) { int e = tid + r * 256; int f = e >> 5, k2 = e & 31;
            float2 v = s2[e]; wlds[PK_W2 + k2 * 64 + f] = pk2(v.x, v.y); }
        const float2* s3 = (const float2*)Ws3;
        #pragma unroll
        for (int r = 0; r < 4; r++) { int e = tid + r * 256; int f = e >> 5, k2 = e & 31;
            float2 v = s3[e]; wlds[PK_W3 + k2 * 32 + f] = pk2(v.x, v.y); }
        const float2* si = (const float2*)Wi1;
        #pragma unroll
        for (int r = 0; r < 16; r++) { int e = tid + r * 256; int f = e >> 6, c2 = e & 63;
            float2 v = si[e]; wlds[PK_WI1 + c2 * 64 + f] = pk2(v.x, v.y); }
        const float2* sc = (const float2*)Wc;
        #pragma unroll
        for (int r = 0; r < 4; r++) { int e = tid + r * 256; int f = e >> 5, c2 = e & 31;
            float2 v = sc[e]; wlds[PK_WC + c2 * 32 + f] = pk2(v.x, v.y); }
    }
    if (blockIdx.x == 0) {
        #pragma unroll
        for (int r = 0; r < 16; r++) { int e = tid + r * 256; wsu[U_W2B + e] = f2bf(Wi2[e] * K2P); }
        #pragma unroll
        for (int r = 0; r < 8; r++)  { int e = tid + r * 256; wsu[U_W3B + e] = f2bf(Wi3[e]); }
        if (tid < HDIM) ws[WS_BI2 + tid] = bi2[tid] * K2P;
        if (tid < LDIM) ws[WS_BI3 + tid] = bi3[tid];
    }

    float sv = (t < 33) ? state[i * 33 + t] : 0.f;
    if (t < 32) shh[w][t] = sv;
    if (t == 32) shph[w] = sv;
    if (t == 33) ws[WS_AGG + i] = fast_sigmoid(aggr[i]);
    __syncthreads();

    {
        float s = bs1[t];
        const unsigned int* W = wlds + PK_W1;
        #pragma unroll
        for (int k2 = 0; k2 < 16; k2++) {
            unsigned int p = W[k2 * 64 + t];
            s = fmaf(blo(p), shh[w][2 * k2], s);
            s = fmaf(bhi(p), shh[w][2 * k2 + 1], s);
        }
        sht1[w][t] = fast_tanh(s);
    }
    __syncthreads();
    {
        float s = bs2[t];
        const unsigned int* W = wlds + PK_W2;
        #pragma unroll
        for (int k2 = 0; k2 < 32; k2++) {
            unsigned int p = W[k2 * 64 + t];
            s = fmaf(blo(p), sht1[w][2 * k2], s);
            s = fmaf(bhi(p), sht1[w][2 * k2 + 1], s);
        }
        sht2[w][t] = fast_tanh(s);
    }
    __syncthreads();
    if (t < 32) {
        float s = bs3[t];
        const unsigned int* W = wlds + PK_W3;
        #pragma unroll
        for (int k2 = 0; k2 < 32; k2++) {
            unsigned int p = W[k2 * 32 + t];
            s = fmaf(blo(p), sht2[w][2 * k2], s);
            s = fmaf(bhi(p), sht2[w][2 * k2 + 1], s);
        }
        ws[WS_SELF + i * 32 + t] = s;
        shdh[w][t] = s;
    }
    __syncthreads();
    {
        float sa = 0.f, sb = bi1[t];
        const unsigned int* W = wlds + PK_WI1;
        #pragma unroll
        for (int k2 = 0; k2 < 16; k2++) {
            float h0 = shh[w][2 * k2], h1 = shh[w][2 * k2 + 1];
            float d0 = shdh[w][2 * k2], d1 = shdh[w][2 * k2 + 1];
            unsigned int wa  = W[k2 * 64 + t];
            unsigned int wb  = W[(16 + k2) * 64 + t];
            unsigned int wa2 = W[(32 + k2) * 64 + t];
            unsigned int wb2 = W[(48 + k2) * 64 + t];
            sa = fmaf(blo(wa), h0, sa);  sa = fmaf(bhi(wa), h1, sa);
            sb = fmaf(blo(wb), h0, sb);  sb = fmaf(bhi(wb), h1, sb);
            sa = fmaf(blo(wa2), d0, sa); sa = fmaf(bhi(wa2), d1, sa);
            sb = fmaf(blo(wb2), d0, sb); sb = fmaf(bhi(wb2), d1, sb);
        }
        ws[WS_AA + i * 64 + t]  = sa * K2P;          // pre-scaled for tanh_pre
        wsu[U_BJB + i * 64 + t] = f2bf(sb * K2P);
    }
    if (t < 32) {
        float si = 0.f, sj = 0.f;
        const unsigned int* W = wlds + PK_WC;
        #pragma unroll
        for (int m2 = 0; m2 < 16; m2++) {
            float h0 = shh[w][2 * m2], h1 = shh[w][2 * m2 + 1];
            unsigned int wi = W[m2 * 32 + t];
            unsigned int wj = W[(16 + m2) * 32 + t];
            si = fmaf(blo(wi), h0, si); si = fmaf(bhi(wi), h1, si);
            sj = fmaf(blo(wj), h0, sj); sj = fmaf(bhi(wj), h1, sj);
        }
        ws[WS_CI + i * 32 + t] = (si + bc[t]) * K1N; // pre-scaled for rcp(1+exp2)
        float h = shh[w][t];
        wsu[U_HJB + i * 32 + t] = f2bf(h);
        float sc, cc;
        __sincosf(shph[w] * phw[t], &sc, &cc);
        uint2 jt; jt.x = pk2(h, sj * K1N); jt.y = pk2(cc, sc);
        *(uint2*)(wsu + U_JT + (i * 32 + t) * 4) = jt;
    }
}

// ------------- kernel 2: MFMA pairwise core (1 block per i) ---------------
// Two j-tiles fused per body: two independent afr->MFMA->epilogue spines
// give the scheduler 2x ILP against the latency chains (occupancy is pinned
// at 4 waves/SIMD by VGPRs, so ILP is the only latency lever). Stage-B
// deferral: B(T-1) at body top, B(T) after epi1, B(T+1) -> next body.
__global__ __launch_bounds__(256) void pair_kernel(
    const float* __restrict__ ws, const unsigned short* __restrict__ wsu,
    float* __restrict__ out) {
    const int i    = blockIdx.x;
    const int tid  = threadIdx.x;
    const int w    = tid >> 6;
    const int lane = tid & 63;
    const int q    = lane >> 4;
    const int m    = lane & 15;
    const int jw   = w * 16;
    const int sub  = lane & 3;

    __shared__ unsigned short W2ls[64 * 72];
    __shared__ unsigned short W3ls[32 * 72];
    __shared__ unsigned short x2ls[4 * 2 * 16 * 72];   // per-wave double buffer
    __shared__ float aLS[64];
    __shared__ float redT[4][32], redU[4][32], redV[4][32];
    __shared__ float sfw[4];

    // ---- setup ----
    if (tid < 64) aLS[tid] = ws[WS_AA + i * 64 + tid];
    {
        int row = tid >> 2, c = (tid & 3) * 16;
        const uint4* s2 = (const uint4*)(wsu + U_W2B + row * 64 + c);
        uint4 d0 = s2[0], d1 = s2[1];
        uint4* dd = (uint4*)(&W2ls[row * 72 + c]);
        dd[0] = d0; dd[1] = d1;
        if (row < 32) {
            const uint4* s3 = (const uint4*)(wsu + U_W3B + row * 64 + c);
            uint4 e0 = s3[0], e1 = s3[1];
            uint4* d3 = (uint4*)(&W3ls[row * 72 + c]);
            d3[0] = e0; d3[1] = e1;
        }
    }
    float hi8[8];
    {
        uint4 hv4 = *(const uint4*)(wsu + U_HJB + i * 32 + sub * 8);
        unsigned int hd[4] = {hv4.x, hv4.y, hv4.z, hv4.w};
        #pragma unroll
        for (int e = 0; e < 4; e++) { hi8[2 * e] = blo(hd[e]); hi8[2 * e + 1] = bhi(hd[e]); }
    }
    f32x4 b2q[4];              // pre-scaled bias slice for MFMA C-init
    #pragma unroll
    for (int nb = 0; nb < 4; nb++) {
        float4 bv = *(const float4*)(ws + WS_BI2 + nb * 16 + q * 4);
        b2q[nb][0] = bv.x; b2q[nb][1] = bv.y; b2q[nb][2] = bv.z; b2q[nb][3] = bv.w;
    }
    float hiv[2], cibv[2];
    #pragma unroll
    for (int lb = 0; lb < 2; lb++) {
        int l = lb * 16 + m;
        hiv[lb]  = bf2f(wsu[U_HJB + i * 32 + l]);
        cibv[lb] = ws[WS_CI + i * 32 + l];
    }
    const float aggi = ws[WS_AGG + i];
    const float sub0 = (sub == 0) ? 1.0f : 0.0f;

    // ---- streaming pointers ----
    const unsigned short* hp = wsu + U_HJB + (jw + (lane >> 2)) * 32 + sub * 8;
    const unsigned short* bp = wsu + U_BJB + (jw + m) * 64 + q * 8;
    const unsigned short* jp = wsu + U_JT + ((jw + q * 4) * 32 + m) * 4;
    __syncthreads();

    // persistent accumulators
    f32x4 accK[2];
    #pragma unroll
    for (int lb = 0; lb < 2; lb++) { accK[lb][0]=0.f; accK[lb][1]=0.f; accK[lb][2]=0.f; accK[lb][3]=0.f; }
    float aU[2] = {0.f, 0.f}, aV[2] = {0.f, 0.f};
    float sumfac = 0.f;

    unsigned short* xb0 = &x2ls[w * 2 * 1152];
    unsigned short* xb1 = xb0 + 1152;

    auto stageB = [&](const unsigned short* xb) {
        bf16x8 x2f[2];
        #pragma unroll
        for (int s = 0; s < 2; s++)
            x2f[s] = *(const bf16x8*)(&xb[m * 72 + s * 32 + q * 8]);
        #pragma unroll
        for (int lb = 0; lb < 2; lb++) {
            #pragma unroll
            for (int s = 0; s < 2; s++) {
                bf16x8 w3f = *(const bf16x8*)(&W3ls[(lb * 16 + m) * 72 + s * 32 + q * 8]);
                accK[lb] = __builtin_amdgcn_mfma_f32_16x16x32_bf16(x2f[s], w3f, accK[lb], 0, 0, 0);
            }
        }
    };

    auto buildAfr = [&](uint4 bA, uint4 bB, bf16x8* afr) {
        unsigned int bd[8] = {bA.x, bA.y, bA.z, bA.w, bB.x, bB.y, bB.z, bB.w};
        #pragma unroll
        for (int s = 0; s < 2; s++) {
            union { uint4 u4; bf16x8 v; } pkd;
            #pragma unroll
            for (int e = 0; e < 4; e++) {
                const float* ab = &aLS[s * 32 + q * 8 + 2 * e];
                float x0 = tanh_pre(ab[0] + blo(bd[s * 4 + e]));
                float x1 = tanh_pre(ab[1] + bhi(bd[s * 4 + e]));
                ((unsigned int*)&pkd.u4)[e] = pk2(x0, x1);
            }
            afr[s] = pkd.v;
        }
    };

    auto stageA = [&](const bf16x8* afr, f32x4* accA) {
        #pragma unroll
        for (int nb = 0; nb < 4; nb++) {
            f32x4 acc = b2q[nb];
            #pragma unroll
            for (int s = 0; s < 2; s++) {
                bf16x8 w2f = *(const bf16x8*)(&W2ls[(nb * 16 + m) * 72 + s * 32 + q * 8]);
                acc = __builtin_amdgcn_mfma_f32_16x16x32_bf16(w2f, afr[s], acc, 0, 0, 0);
            }
            accA[nb] = acc;
        }
    };

    auto epiA = [&](const f32x4* accA, float facm, unsigned short* xcur) {
        const float fm2 = -2.0f * facm;
        #pragma unroll
        for (int nb = 0; nb < 4; nb++) {
            float r0 = fast_rcp(__builtin_amdgcn_exp2f(accA[nb][0]) + 1.0f);
            float r1 = fast_rcp(__builtin_amdgcn_exp2f(accA[nb][1]) + 1.0f);
            float r2 = fast_rcp(__builtin_amdgcn_exp2f(accA[nb][2]) + 1.0f);
            float r3 = fast_rcp(__builtin_amdgcn_exp2f(accA[nb][3]) + 1.0f);
            float t0 = fmaf(fm2, r0, facm), t1 = fmaf(fm2, r1, facm);
            float t2 = fmaf(fm2, r2, facm), t3 = fmaf(fm2, r3, facm);
            uint2 pk; pk.x = pk2(t0, t1); pk.y = pk2(t2, t3);
            *(uint2*)(&xcur[m * 72 + nb * 16 + q * 4]) = pk;
        }
    };

    auto stageC = [&](const uint2* jt) {
        #pragma unroll
        for (int lb = 0; lb < 2; lb++) {
            float u = 0.f, v = 0.f;
            #pragma unroll
            for (int r = 0; r < 4; r++) {
                uint2 jv = jt[lb * 4 + r];
                float hj = blo(jv.x), cj = bhi(jv.x);
                float pjc = blo(jv.y), pjs = bhi(jv.y);
                float coh = fast_rcp(1.0f + __builtin_amdgcn_exp2f(cibv[lb] + cj));
                float cd  = coh * (hiv[lb] - hj);
                u = fmaf(cd, pjc, u);
                v = fmaf(cd, pjs, v);
            }
            aU[lb] += u; aV[lb] += v;
        }
    };

    auto facOf = [&](uint4 hv, int jj) -> float {
        unsigned int hd[4] = {hv.x, hv.y, hv.z, hv.w};
        float s = 0.f;
        #pragma unroll
        for (int e = 0; e < 4; e++) {
            float d0 = hi8[2 * e]     - blo(hd[e]);
            float d1 = hi8[2 * e + 1] - bhi(hd[e]);
            s = fmaf(d0, d0, s); s = fmaf(d1, d1, s);
        }
        s += __shfl_xor(s, 1); s += __shfl_xor(s, 2);
        float f = fminf(__builtin_amdgcn_rsqf(s), 2.0f) * aggi;
        return (jj == i) ? 0.0f : f;
    };

    #pragma unroll 1
    for (int TP = 0; TP < 16; TP += 2) {
        // loads for both tiles
        uint4 hv0 = *(const uint4*)hp;
        uint4 hv1 = *(const uint4*)(hp + 2048);
        hp += 4096;
        uint4 b00 = *(const uint4*)bp;
        uint4 b01 = *(const uint4*)(bp + 32);
        uint4 b10 = *(const uint4*)(bp + 4096);
        uint4 b11 = *(const uint4*)(bp + 4128);
        bp += 8192;
        uint2 jt0[8];
        #pragma unroll
        for (int r = 0; r < 4; r++) {
            jt0[r]     = *(const uint2*)(jp + r * 128);
            jt0[4 + r] = *(const uint2*)(jp + 64 + r * 128);
        }

        // deferred stage B for tile TP-1
        if (TP > 0) stageB(xb1);

        // fac for both tiles (independent cross-lane chains)
        int jj0 = TP * 64 + jw + (lane >> 2);
        float f0 = facOf(hv0, jj0);
        float f1 = facOf(hv1, jj0 + 64);
        sumfac = fmaf(sub0, f0, sumfac);
        sumfac = fmaf(sub0, f1, sumfac);
        float facm0 = __shfl(f0, 4 * m);
        float facm1 = __shfl(f1, 4 * m);

        // two independent tanh bursts (32 chains of ILP)
        bf16x8 afr0[2], afr1[2];
        buildAfr(b00, b01, afr0);
        buildAfr(b10, b11, afr1);

        // two independent MFMA groups
        f32x4 accA0[4], accA1[4];
        stageA(afr0, accA0);
        stageA(afr1, accA1);

        // two independent epilogues
        epiA(accA0, facm0, xb0);
        epiA(accA1, facm1, xb1);

        // stage B for tile TP (epi1 sits between write and read)
        stageB(xb0);

        // stage C tile TP, then late-load jt1 + stage C tile TP+1
        stageC(jt0);
        uint2 jt1[8];
        #pragma unroll
        for (int r = 0; r < 4; r++) {
            jt1[r]     = *(const uint2*)(jp + 8192 + r * 128);
            jt1[4 + r] = *(const uint2*)(jp + 8192 + 64 + r * 128);
        }
        jp += 16384;
        stageC(jt1);
    }
    stageB(xb1);   // tile 15

    // ---- final reductions ----
    float T1[2];
    #pragma unroll
    for (int lb = 0; lb < 2; lb++) {
        T1[lb] = (accK[lb][0] + accK[lb][1]) + (accK[lb][2] + accK[lb][3]);
        T1[lb] += __shfl_xor(T1[lb], 16); T1[lb] += __shfl_xor(T1[lb], 32);
        aU[lb] += __shfl_xor(aU[lb], 16); aU[lb] += __shfl_xor(aU[lb], 32);
        aV[lb] += __shfl_xor(aV[lb], 16); aV[lb] += __shfl_xor(aV[lb], 32);
    }
    sumfac += __shfl_xor(sumfac, 1);  sumfac += __shfl_xor(sumfac, 2);
    sumfac += __shfl_xor(sumfac, 4);  sumfac += __shfl_xor(sumfac, 8);
    sumfac += __shfl_xor(sumfac, 16); sumfac += __shfl_xor(sumfac, 32);
    if (lane < 16) {
        redT[w][m] = T1[0];      redT[w][16 + m] = T1[1];
        redU[w][m] = aU[0];      redU[w][16 + m] = aU[1];
        redV[w][m] = aV[0];      redV[w][16 + m] = aV[1];
    }
    if (lane == 0) sfw[w] = sumfac;
    __syncthreads();
    if (tid < 32) {
        int l = tid;
        float t1 = (redT[0][l] + redT[1][l]) + (redT[2][l] + redT[3][l]);
        float uu = (redU[0][l] + redU[1][l]) + (redU[2][l] + redU[3][l]);
        float vv = (redV[0][l] + redV[1][l]) + (redV[2][l] + redV[3][l]);
        float sf = (sfw[0] + sfw[1]) + (sfw[2] + sfw[3]);
        uint2 jti = *(const uint2*)(wsu + U_JT + (i * 32 + l) * 4);
        float pic = blo(jti.y), pis = bhi(jti.y);
        float isum = t1 + sf * ws[WS_BI3 + l] - (pic * uu + pis * vv);
        out[i * 33 + l] = 0.5f * ws[WS_SELF + i * 32 + l] + 0.3f * isum;
        redT[0][l] = fabsf(isum);
    }
    __syncthreads();
    if (tid == 0) {
        float s = 0.f;
        #pragma unroll
        for (int l = 0; l < 32; l++) s += redT[0][l];
        out[i * 33 + 32] = 0.1f + 0.05f * s;
    }
}

extern "C" void kernel_launch(void* const* d_in, const int* in_sizes, int n_in,
                              void* d_out, int out_size, void* d_ws, size_t ws_size,
                              hipStream_t stream) {
    const float* state   = (const float*)d_in[0];
    const float* Ws1     = (const float*)d_in[1];
    const float* bs1     = (const float*)d_in[2];
    const float* Ws2     = (const float*)d_in[3];
    const float* bs2     = (const float*)d_in[4];
    const float* Ws3     = (const float*)d_in[5];
    const float* bs3     = (const float*)d_in[6];
    const float* Wi1     = (const float*)d_in[7];
    const float* bi1     = (const float*)d_in[8];
    const float* Wi2     = (const float*)d_in[9];
    const float* bi2     = (const float*)d_in[10];
    const float* Wi3     = (const float*)d_in[11];
    const float* bi3     = (const float*)d_in[12];
    const float* phase_w = (const float*)d_in[13];
    const float* Wc      = (const float*)d_in[14];
    const float* bc      = (const float*)d_in[15];
    const float* aggr    = (const float*)d_in[16];

    float* ws = (float*)d_ws;
    unsigned short* wsu = (unsigned short*)(ws + WS_FEND);
    float* out = (float*)d_out;

    precompute<<<256, 256, 0, stream>>>(state, Ws1, bs1, Ws2, bs2, Ws3, bs3,
                                        Wi1, bi1, Wi2, bi2, Wi3, bi3,
                                        phase_w, Wc, bc, aggr, ws, wsu);
    pair_kernel<<<NN, 256, 0, stream>>>(ws, wsu, out);
}

// Round 12
// 152.249 us; speedup vs baseline: 1.0377x; 1.0023x over previous
//
#include <hip/hip_runtime.h>
#include <hip/hip_bf16.h>
#include <math.h>

#define NN 1024
#define LDIM 32
#define HDIM 64

// ---------------- fp32 workspace layout (float offsets) ----------------
#define WS_SELF 0                        // N*L   self_term [i][l]
#define WS_AA   (WS_SELF + NN*LDIM)      // N*H   a_i [i][h]  (unscaled)
#define WS_CI   (WS_AA   + NN*HDIM)      // N*L   0.5*(ci+bc) [i][l]
#define WS_AGG  (WS_CI   + NN*LDIM)      // N     sigmoid(aggr)
#define WS_BI2  (WS_AGG  + NN)           // H     bi2 (unscaled)
#define WS_BI3  (WS_BI2  + HDIM)         // L     bi3 (unscaled)
#define WS_FEND (WS_BI3  + LDIM)

// ---------------- bf16(u16) region (short offsets from wsu) -------------
#define U_BJB  0                         // N*H   b_j [j][h]  (unscaled)
#define U_HJB  (U_BJB + NN*HDIM)         // N*L   h   [j][l]
#define U_JT   (U_HJB + NN*LDIM)         // N*L*4 interleaved {h, 0.5*cj | pc, ps}
#define U_W2B  (U_JT  + NN*LDIM*4)       // H*H   Wi2 [n][k] (unscaled)
#define U_W3B  (U_W2B + HDIM*HDIM)       // L*H   Wi3 [l][k] (unscaled)
#define U_END  (U_W3B + LDIM*HDIM)

// packed-pair transposed weight tables in precompute LDS (uint offsets)
#define PK_W1  0        // 16*64   Ws1
#define PK_W2  1024     // 32*64   Ws2
#define PK_W3  3072     // 32*32   Ws3
#define PK_WI1 4096     // 64*64   Wi1
#define PK_WC  8192     // 32*32   Wc
#define PK_END 9216     // 36 KB

#define K2P  2.88539008f     // 2*log2(e)   (precompute-only)
#define K1N  (-1.44269504f)  // -log2(e)    (precompute-only)

typedef __attribute__((ext_vector_type(8))) short bf16x8;
typedef __attribute__((ext_vector_type(4))) float f32x4;

__device__ __forceinline__ float fast_rcp(float x) { return __builtin_amdgcn_rcpf(x); }
__device__ __forceinline__ float fast_tanh(float x) {          // precompute-only
    float e = __builtin_amdgcn_exp2f(x * K2P);
    return 1.0f - 2.0f * fast_rcp(e + 1.0f);
}
__device__ __forceinline__ float fast_sigmoid(float x) {       // precompute-only
    return fast_rcp(1.0f + __builtin_amdgcn_exp2f(x * K1N));
}
// Pure-FMA tanh: x*P5(x^2), Chebyshev-fit on [-3.5,3.5], |err| <= ~0.007.
// 8 VALU ops (16 cy) vs exp2+rcp path (36 cy) -- no quarter-rate trans ops.
__device__ __forceinline__ float tanh_poly(float x) {
    float xc = fminf(fmaxf(x, -3.5f), 3.5f);
    float u = xc * xc;
    float f = fmaf(u, -0.0000131383f, 0.000515254f);
    f = fmaf(u, f, -0.00792753f);
    f = fmaf(u, f, 0.0619482f);
    f = fmaf(u, f, -0.278313f);
    f = fmaf(u, f, 0.991232f);
    return xc * f;
}
__device__ __forceinline__ float blo(unsigned int u) { union { unsigned int i; float f; } v; v.i = u << 16; return v.f; }
__device__ __forceinline__ float bhi(unsigned int u) { union { unsigned int i; float f; } v; v.i = u & 0xffff0000u; return v.f; }
__device__ __forceinline__ float bf2f(unsigned short u) { union { unsigned int i; float f; } v; v.i = ((unsigned int)u) << 16; return v.f; }
__device__ __forceinline__ unsigned short f2bf(float f) {
    __hip_bfloat16 b = __float2bfloat16(f);
    unsigned short u; __builtin_memcpy(&u, &b, 2); return u;
}
__device__ __forceinline__ unsigned int pk2(float a, float b) {
    float2 t; t.x = a; t.y = b;
    __hip_bfloat162 h = __float22bfloat162_rn(t);
    unsigned int u; __builtin_memcpy(&u, &h, 4); return u;
}

// ------------- kernel 1: precompute (weights packed in-block) -------------
__global__ __launch_bounds__(256) void precompute(
    const float* __restrict__ state,
    const float* __restrict__ Ws1, const float* __restrict__ bs1,
    const float* __restrict__ Ws2, const float* __restrict__ bs2,
    const float* __restrict__ Ws3, const float* __restrict__ bs3,
    const float* __restrict__ Wi1, const float* __restrict__ bi1,
    const float* __restrict__ Wi2, const float* __restrict__ bi2,
    const float* __restrict__ Wi3, const float* __restrict__ bi3,
    const float* __restrict__ phw, const float* __restrict__ Wc,
    const float* __restrict__ bc,  const float* __restrict__ aggr,
    float* __restrict__ ws, unsigned short* __restrict__ wsu) {
    const int tid = threadIdx.x;
    const int w = tid >> 6, t = tid & 63;
    const int i = blockIdx.x * 4 + w;

    __shared__ unsigned int wlds[PK_END];
    __shared__ float shh[4][32], shdh[4][32], sht1[4][64], sht2[4][64];
    __shared__ float shph[4];

    {
        const float2* s1 = (const float2*)Ws1;
        #pragma unroll
        for (int r = 0; r < 4; r++) { int e = tid + r * 256; int f = e >> 4, k2 = e & 15;
            float2 v = s1[e]; wlds[PK_W1 + k2 * 64 + f] = pk2(v.x, v.y); }
        const float2* s2 = (const float2*)Ws2;
        #pragma unroll
        for (int r = 0; r < 8; r++) { int e = tid + r * 256; int f = e >> 5, k2 = e & 31;
            float2 v = s2[e]; wlds[PK_W2 + k2 * 64 + f] = pk2(v.x, v.y); }
        const float2* s3 = (const float2*)Ws3;
        #pragma unroll
        for (int r = 0; r < 4; r++) { int e = tid + r * 256; int f = e >> 5, k2 = e & 31;
            float2 v = s3[e]; wlds[PK_W3 + k2 * 32 + f] = pk2(v.x, v.y); }
        const float2* si = (const float2*)Wi1;
        #pragma unroll
        for (int r = 0; r < 16; r++) { int e = tid + r * 256; int f = e >> 6, c2 = e & 63;
            float2 v = si[e]; wlds[PK_WI1 + c2 * 64 + f] = pk2(v.x, v.y); }
        const float2* sc = (const float2*)Wc;
        #pragma unroll
        for (int r = 0; r < 4; r++) { int e = tid + r * 256; int f = e >> 5, c2 = e & 31;
            float2 v = sc[e]; wlds[PK_WC + c2 * 32 + f] = pk2(v.x, v.y); }
    }
    if (blockIdx.x == 0) {
        #pragma unroll
        for (int r = 0; r < 16; r++) { int e = tid + r * 256; wsu[U_W2B + e] = f2bf(Wi2[e]); }
        #pragma unroll
        for (int r = 0; r < 8; r++)  { int e = tid + r * 256; wsu[U_W3B + e] = f2bf(Wi3[e]); }
        if (tid < HDIM) ws[WS_BI2 + tid] = bi2[tid];
        if (tid < LDIM) ws[WS_BI3 + tid] = bi3[tid];
    }

    float sv = (t < 33) ? state[i * 33 + t] : 0.f;
    if (t < 32) shh[w][t] = sv;
    if (t == 32) shph[w] = sv;
    if (t == 33) ws[WS_AGG + i] = fast_sigmoid(aggr[i]);
    __syncthreads();

    {
        float s = bs1[t];
        const unsigned int* W = wlds + PK_W1;
        #pragma unroll
        for (int k2 = 0; k2 < 16; k2++) {
            unsigned int p = W[k2 * 64 + t];
            s = fmaf(blo(p), shh[w][2 * k2], s);
            s = fmaf(bhi(p), shh[w][2 * k2 + 1], s);
        }
        sht1[w][t] = fast_tanh(s);
    }
    __syncthreads();
    {
        float s = bs2[t];
        const unsigned int* W = wlds + PK_W2;
        #pragma unroll
        for (int k2 = 0; k2 < 32; k2++) {
            unsigned int p = W[k2 * 64 + t];
            s = fmaf(blo(p), sht1[w][2 * k2], s);
            s = fmaf(bhi(p), sht1[w][2 * k2 + 1], s);
        }
        sht2[w][t] = fast_tanh(s);
    }
    __syncthreads();
    if (t < 32) {
        float s = bs3[t];
        const unsigned int* W = wlds + PK_W3;
        #pragma unroll
        for (int k2 = 0; k2 < 32; k2++) {
            unsigned int p = W[k2 * 32 + t];
            s = fmaf(blo(p), sht2[w][2 * k2], s);
            s = fmaf(bhi(p), sht2[w][2 * k2 + 1], s);
        }
        ws[WS_SELF + i * 32 + t] = s;
        shdh[w][t] = s;
    }
    __syncthreads();
    {
        float sa = 0.f, sb = bi1[t];
        const unsigned int* W = wlds + PK_WI1;
        #pragma unroll
        for (int k2 = 0; k2 < 16; k2++) {
            float h0 = shh[w][2 * k2], h1 = shh[w][2 * k2 + 1];
            float d0 = shdh[w][2 * k2], d1 = shdh[w][2 * k2 + 1];
            unsigned int wa  = W[k2 * 64 + t];
            unsigned int wb  = W[(16 + k2) * 64 + t];
            unsigned int wa2 = W[(32 + k2) * 64 + t];
            unsigned int wb2 = W[(48 + k2) * 64 + t];
            sa = fmaf(blo(wa), h0, sa);  sa = fmaf(bhi(wa), h1, sa);
            sb = fmaf(blo(wb), h0, sb);  sb = fmaf(bhi(wb), h1, sb);
            sa = fmaf(blo(wa2), d0, sa); sa = fmaf(bhi(wa2), d1, sa);
            sb = fmaf(blo(wb2), d0, sb); sb = fmaf(bhi(wb2), d1, sb);
        }
        ws[WS_AA + i * 64 + t]  = sa;
        wsu[U_BJB + i * 64 + t] = f2bf(sb);
    }
    if (t < 32) {
        float si = 0.f, sj = 0.f;
        const unsigned int* W = wlds + PK_WC;
        #pragma unroll
        for (int m2 = 0; m2 < 16; m2++) {
            float h0 = shh[w][2 * m2], h1 = shh[w][2 * m2 + 1];
            unsigned int wi = W[m2 * 32 + t];
            unsigned int wj = W[(16 + m2) * 32 + t];
            si = fmaf(blo(wi), h0, si); si = fmaf(bhi(wi), h1, si);
            sj = fmaf(blo(wj), h0, sj); sj = fmaf(bhi(wj), h1, sj);
        }
        ws[WS_CI + i * 32 + t] = (si + bc[t]) * 0.5f;   // halved: sigmoid(z)=0.5+0.5*tanh(z/2)
        float h = shh[w][t];
        wsu[U_HJB + i * 32 + t] = f2bf(h);
        float sc, cc;
        __sincosf(shph[w] * phw[t], &sc, &cc);
        uint2 jt; jt.x = pk2(h, sj * 0.5f); jt.y = pk2(cc, sc);
        *(uint2*)(wsu + U_JT + (i * 32 + t) * 4) = jt;
    }
}

// ------------- kernel 2: MFMA pairwise core (1 block per i) ---------------
// r8 structure (best verified) with every in-loop transcendental replaced by
// the pure-FMA tanh_poly: 80 quarter-rate trans ops/body -> 0. Sigmoid coh
// via 0.5+0.5*tanh(z/2) with the halving folded into precomputed ci/cj.
__global__ __launch_bounds__(256) void pair_kernel(
    const float* __restrict__ ws, const unsigned short* __restrict__ wsu,
    float* __restrict__ out) {
    const int i    = blockIdx.x;
    const int tid  = threadIdx.x;
    const int w    = tid >> 6;
    const int lane = tid & 63;
    const int q    = lane >> 4;
    const int m    = lane & 15;
    const int jw   = w * 16;
    const int sub  = lane & 3;

    __shared__ unsigned short W2ls[64 * 72];
    __shared__ unsigned short W3ls[32 * 72];
    __shared__ unsigned short x2ls[4 * 2 * 16 * 72];   // per-wave double buffer
    __shared__ float aLS[64];
    __shared__ float redT[4][32], redU[4][32], redV[4][32];
    __shared__ float sfw[4];

    // ---- setup ----
    if (tid < 64) aLS[tid] = ws[WS_AA + i * 64 + tid];
    {
        int row = tid >> 2, c = (tid & 3) * 16;
        const uint4* s2 = (const uint4*)(wsu + U_W2B + row * 64 + c);
        uint4 d0 = s2[0], d1 = s2[1];
        uint4* dd = (uint4*)(&W2ls[row * 72 + c]);
        dd[0] = d0; dd[1] = d1;
        if (row < 32) {
            const uint4* s3 = (const uint4*)(wsu + U_W3B + row * 64 + c);
            uint4 e0 = s3[0], e1 = s3[1];
            uint4* d3 = (uint4*)(&W3ls[row * 72 + c]);
            d3[0] = e0; d3[1] = e1;
        }
    }
    float hi8[8];
    {
        uint4 hv4 = *(const uint4*)(wsu + U_HJB + i * 32 + sub * 8);
        unsigned int hd[4] = {hv4.x, hv4.y, hv4.z, hv4.w};
        #pragma unroll
        for (int e = 0; e < 4; e++) { hi8[2 * e] = blo(hd[e]); hi8[2 * e + 1] = bhi(hd[e]); }
    }
    f32x4 b2q[4];              // bias slice for MFMA C-init
    #pragma unroll
    for (int nb = 0; nb < 4; nb++) {
        float4 bv = *(const float4*)(ws + WS_BI2 + nb * 16 + q * 4);
        b2q[nb][0] = bv.x; b2q[nb][1] = bv.y; b2q[nb][2] = bv.z; b2q[nb][3] = bv.w;
    }
    float hiv[2], cibv[2];
    #pragma unroll
    for (int lb = 0; lb < 2; lb++) {
        int l = lb * 16 + m;
        hiv[lb]  = bf2f(wsu[U_HJB + i * 32 + l]);
        cibv[lb] = ws[WS_CI + i * 32 + l];        // pre-halved (ci+bc)/2
    }
    const float aggi = ws[WS_AGG + i];
    const float sub0 = (sub == 0) ? 1.0f : 0.0f;

    // ---- streaming pointers + tile-0 prefetch ----
    const unsigned short* hp = wsu + U_HJB + (jw + (lane >> 2)) * 32 + sub * 8;
    const unsigned short* bp = wsu + U_BJB + (jw + m) * 64 + q * 8;
    const unsigned short* jp = wsu + U_JT + ((jw + q * 4) * 32 + m) * 4;

    uint4 hvA = *(const uint4*)hp;
    uint4 b0A = *(const uint4*)bp;
    uint4 b1A = *(const uint4*)(bp + 32);
    uint4 hvB, b0B, b1B;
    __syncthreads();

    // persistent accumulators
    f32x4 accK[2];
    #pragma unroll
    for (int lb = 0; lb < 2; lb++) { accK[lb][0]=0.f; accK[lb][1]=0.f; accK[lb][2]=0.f; accK[lb][3]=0.f; }
    float aU[2] = {0.f, 0.f}, aV[2] = {0.f, 0.f};
    float sumfac = 0.f;

    unsigned short* xb0 = &x2ls[w * 2 * 1152];
    unsigned short* xb1 = xb0 + 1152;

    auto stageB = [&](const unsigned short* xb) {
        bf16x8 x2f[2];
        #pragma unroll
        for (int s = 0; s < 2; s++)
            x2f[s] = *(const bf16x8*)(&xb[m * 72 + s * 32 + q * 8]);
        #pragma unroll
        for (int lb = 0; lb < 2; lb++) {
            #pragma unroll
            for (int s = 0; s < 2; s++) {
                bf16x8 w3f = *(const bf16x8*)(&W3ls[(lb * 16 + m) * 72 + s * 32 + q * 8]);
                accK[lb] = __builtin_amdgcn_mfma_f32_16x16x32_bf16(x2f[s], w3f, accK[lb], 0, 0, 0);
            }
        }
    };

    auto body = [&](int T, uint4 hvc, uint4 b0c, uint4 b1c,
                    uint4& hvn, uint4& b0n, uint4& b1n,
                    unsigned short* xcur, const unsigned short* xprev) {
        // prefetch next tile's h/b
        hp += 2048; bp += 4096;
        hvn = *(const uint4*)hp;
        b0n = *(const uint4*)bp;
        b1n = *(const uint4*)(bp + 32);
        // jt loads for CURRENT tile (consumed at body end)
        uint2 jt[8];
        #pragma unroll
        for (int r = 0; r < 4; r++) {
            jt[r]     = *(const uint2*)(jp + r * 128);
            jt[4 + r] = *(const uint2*)(jp + 64 + r * 128);
        }
        jp += 8192;

        // deferred stage B for previous tile (LDS data a full body old)
        if (T > 0) stageB(xprev);

        // 1) fac (lane owns j = T*64 + jw + (lane>>2)); zeroed at j==i
        float facm;
        {
            unsigned int hd[4] = {hvc.x, hvc.y, hvc.z, hvc.w};
            float s = 0.f;
            #pragma unroll
            for (int e = 0; e < 4; e++) {
                float d0 = hi8[2 * e]     - blo(hd[e]);
                float d1 = hi8[2 * e + 1] - bhi(hd[e]);
                s = fmaf(d0, d0, s); s = fmaf(d1, d1, s);
            }
            s += __shfl_xor(s, 1); s += __shfl_xor(s, 2);
            int jj = T * 64 + jw + (lane >> 2);
            float facown = fminf(__builtin_amdgcn_rsqf(s), 2.0f) * aggi;
            facown = (jj == i) ? 0.0f : facown;
            sumfac = fmaf(sub0, facown, sumfac);
            facm = __shfl(facown, 4 * m);
        }

        // 2) x1 B-fragments: tanh_poly (pure FMA)
        bf16x8 afr[2];
        {
            unsigned int bd[8] = {b0c.x, b0c.y, b0c.z, b0c.w, b1c.x, b1c.y, b1c.z, b1c.w};
            #pragma unroll
            for (int s = 0; s < 2; s++) {
                union { uint4 u4; bf16x8 v; } pkd;
                #pragma unroll
                for (int e = 0; e < 4; e++) {
                    const float* ab = &aLS[s * 32 + q * 8 + 2 * e];
                    float x0 = tanh_poly(ab[0] + blo(bd[s * 4 + e]));
                    float x1 = tanh_poly(ab[1] + bhi(bd[s * 4 + e]));
                    ((unsigned int*)&pkd.u4)[e] = pk2(x0, x1);
                }
                afr[s] = pkd.v;
            }
        }

        // 3) stage A: X2^T = Wi2 * X1^T, C-init = bias
        f32x4 accA[4];
        #pragma unroll
        for (int nb = 0; nb < 4; nb++) {
            f32x4 acc = b2q[nb];
            #pragma unroll
            for (int s = 0; s < 2; s++) {
                bf16x8 w2f = *(const bf16x8*)(&W2ls[(nb * 16 + m) * 72 + s * 32 + q * 8]);
                acc = __builtin_amdgcn_mfma_f32_16x16x32_bf16(w2f, afr[s], acc, 0, 0, 0);
            }
            accA[nb] = acc;
        }
        // epilogue A: x2s = fac * tanh_poly(acc)
        #pragma unroll
        for (int nb = 0; nb < 4; nb++) {
            float t0 = facm * tanh_poly(accA[nb][0]);
            float t1 = facm * tanh_poly(accA[nb][1]);
            float t2 = facm * tanh_poly(accA[nb][2]);
            float t3 = facm * tanh_poly(accA[nb][3]);
            uint2 pk; pk.x = pk2(t0, t1); pk.y = pk2(t2, t3);
            *(uint2*)(&xcur[m * 72 + nb * 16 + q * 4]) = pk;
        }

        // 5) stage C: quantum-term partials; coh = 0.5 + 0.5*tanh(z/2)
        #pragma unroll
        for (int lb = 0; lb < 2; lb++) {
            float u = 0.f, v = 0.f;
            #pragma unroll
            for (int r = 0; r < 4; r++) {
                uint2 jv = jt[lb * 4 + r];
                float hj = blo(jv.x), cjh = bhi(jv.x);     // cjh = cj/2
                float pjc = blo(jv.y), pjs = bhi(jv.y);
                float coh = fmaf(0.5f, tanh_poly(cibv[lb] + cjh), 0.5f);
                float cd  = coh * (hiv[lb] - hj);
                u = fmaf(cd, pjc, u);
                v = fmaf(cd, pjs, v);
            }
            aU[lb] += u; aV[lb] += v;
        }
    };

    #pragma unroll 1
    for (int T = 0; T < 16; T += 2) {
        body(T,     hvA, b0A, b1A, hvB, b0B, b1B, xb0, xb1);
        body(T + 1, hvB, b0B, b1B, hvA, b0A, b1A, xb1, xb0);
    }
    stageB(xb1);   // tile 15

    // ---- final reductions ----
    float T1[2];
    #pragma unroll
    for (int lb = 0; lb < 2; lb++) {
        T1[lb] = (accK[lb][0] + accK[lb][1]) + (accK[lb][2] + accK[lb][3]);
        T1[lb] += __shfl_xor(T1[lb], 16); T1[lb] += __shfl_xor(T1[lb], 32);
        aU[lb] += __shfl_xor(aU[lb], 16); aU[lb] += __shfl_xor(aU[lb], 32);
        aV[lb] += __shfl_xor(aV[lb], 16); aV[lb] += __shfl_xor(aV[lb], 32);
    }
    sumfac += __shfl_xor(sumfac, 1);  sumfac += __shfl_xor(sumfac, 2);
    sumfac += __shfl_xor(sumfac, 4);  sumfac += __shfl_xor(sumfac, 8);
    sumfac += __shfl_xor(sumfac, 16); sumfac += __shfl_xor(sumfac, 32);
    if (lane < 16) {
        redT[w][m] = T1[0];      redT[w][16 + m] = T1[1];
        redU[w][m] = aU[0];      redU[w][16 + m] = aU[1];
        redV[w][m] = aV[0];      redV[w][16 + m] = aV[1];
    }
    if (lane == 0) sfw[w] = sumfac;
    __syncthreads();
    if (tid < 32) {
        int l = tid;
        float t1 = (redT[0][l] + redT[1][l]) + (redT[2][l] + redT[3][l]);
        float uu = (redU[0][l] + redU[1][l]) + (redU[2][l] + redU[3][l]);
        float vv = (redV[0][l] + redV[1][l]) + (redV[2][l] + redV[3][l]);
        float sf = (sfw[0] + sfw[1]) + (sfw[2] + sfw[3]);
        uint2 jti = *(const uint2*)(wsu + U_JT + (i * 32 + l) * 4);
        float pic = blo(jti.y), pis = bhi(jti.y);
        float isum = t1 + sf * ws[WS_BI3 + l] - (pic * uu + pis * vv);
        out[i * 33 + l] = 0.5f * ws[WS_SELF + i * 32 + l] + 0.3f * isum;
        redT[0][l] = fabsf(isum);
    }
    __syncthreads();
    if (tid == 0) {
        float s = 0.f;
        #pragma unroll
        for (int l = 0; l < 32; l++) s += redT[0][l];
        out[i * 33 + 32] = 0.1f + 0.05f * s;
    }
}

extern "C" void kernel_launch(void* const* d_in, const int* in_sizes, int n_in,
                              void* d_out, int out_size, void* d_ws, size_t ws_size,
                              hipStream_t stream) {
    const float* state   = (const float*)d_in[0];
    const float* Ws1     = (const float*)d_in[1];
    const float* bs1     = (const float*)d_in[2];
    const float* Ws2     = (const float*)d_in[3];
    const float* bs2     = (const float*)d_in[4];
    const float* Ws3     = (const float*)d_in[5];
    const float* bs3     = (const float*)d_in[6];
    const float* Wi1     = (const float*)d_in[7];
    const float* bi1     = (const float*)d_in[8];
    const float* Wi2     = (const float*)d_in[9];
    const float* bi2     = (const float*)d_in[10];
    const float* Wi3     = (const float*)d_in[11];
    const float* bi3     = (const float*)d_in[12];
    const float* phase_w = (const float*)d_in[13];
    const float* Wc      = (const float*)d_in[14];
    const float* bc      = (const float*)d_in[15];
    const float* aggr    = (const float*)d_in[16];

    float* ws = (float*)d_ws;
    unsigned short* wsu = (unsigned short*)(ws + WS_FEND);
    float* out = (float*)d_out;

    precompute<<<256, 256, 0, stream>>>(state, Ws1, bs1, Ws2, bs2, Ws3, bs3,
                                        Wi1, bi1, Wi2, bi2, Wi3, bi3,
                                        phase_w, Wc, bc, aggr, ws, wsu);
    pair_kernel<<<NN, 256, 0, stream>>>(ws, wsu, out);
}

// Round 13
// 151.086 us; speedup vs baseline: 1.0457x; 1.0077x over previous
//
#include <hip/hip_runtime.h>
#include <hip/hip_bf16.h>
#include <math.h>

#define NN 1024
#define LDIM 32
#define HDIM 64

// ---------------- fp32 workspace layout (float offsets) ----------------
#define WS_SELF 0                        // N*L   self_term [i][l]
#define WS_AA   (WS_SELF + NN*LDIM)      // N*H   a_i [i][h]  (pre-scaled by 2log2e)
#define WS_CI   (WS_AA   + NN*HDIM)      // N*L   -log2e*(ci+bc) [i][l]
#define WS_AGG  (WS_CI   + NN*LDIM)      // N     sigmoid(aggr)
#define WS_BI2  (WS_AGG  + NN)           // H     bi2 * 2log2e
#define WS_BI3  (WS_BI2  + HDIM)         // L     bi3 (unscaled)
#define WS_FEND (WS_BI3  + LDIM)

// ---------------- bf16(u16) region (short offsets from wsu) -------------
#define U_BJB  0                         // N*H   b_j [j][h]  (pre-scaled by 2log2e)
#define U_HJB  (U_BJB + NN*HDIM)         // N*L   h   [j][l]
#define U_JT   (U_HJB + NN*LDIM)         // N*L*4 interleaved {h, -log2e*cj | pc, ps}
#define U_W2B  (U_JT  + NN*LDIM*4)       // H*H   Wi2 [n][k] * 2log2e
#define U_W3B  (U_W2B + HDIM*HDIM)       // L*H   Wi3 [l][k] (unscaled)
#define U_END  (U_W3B + LDIM*HDIM)

// packed-pair transposed weight tables in precompute LDS (uint offsets)
#define PK_W1  0        // 16*64   Ws1
#define PK_W2  1024     // 32*64   Ws2
#define PK_W3  3072     // 32*32   Ws3
#define PK_WI1 4096     // 64*64   Wi1
#define PK_WC  8192     // 32*32   Wc
#define PK_END 9216     // 36 KB

#define K2P  2.88539008f     // 2*log2(e)
#define K1N  (-1.44269504f)  // -log2(e)

typedef __attribute__((ext_vector_type(8))) short bf16x8;
typedef __attribute__((ext_vector_type(4))) float f32x4;

__device__ __forceinline__ float fast_rcp(float x) { return __builtin_amdgcn_rcpf(x); }
__device__ __forceinline__ float fast_tanh(float x) {          // full version (precompute)
    float e = __builtin_amdgcn_exp2f(x * K2P);
    return 1.0f - 2.0f * fast_rcp(e + 1.0f);
}
__device__ __forceinline__ float tanh_pre(float xp) {          // input pre-scaled by 2log2e
    return 1.0f - 2.0f * fast_rcp(__builtin_amdgcn_exp2f(xp) + 1.0f);
}
__device__ __forceinline__ float fast_sigmoid(float x) {       // full version (precompute)
    return fast_rcp(1.0f + __builtin_amdgcn_exp2f(x * K1N));
}
__device__ __forceinline__ float blo(unsigned int u) { union { unsigned int i; float f; } v; v.i = u << 16; return v.f; }
__device__ __forceinline__ float bhi(unsigned int u) { union { unsigned int i; float f; } v; v.i = u & 0xffff0000u; return v.f; }
__device__ __forceinline__ float bf2f(unsigned short u) { union { unsigned int i; float f; } v; v.i = ((unsigned int)u) << 16; return v.f; }
__device__ __forceinline__ unsigned short f2bf(float f) {
    __hip_bfloat16 b = __float2bfloat16(f);
    unsigned short u; __builtin_memcpy(&u, &b, 2); return u;
}
__device__ __forceinline__ unsigned int pk2(float a, float b) {
    float2 t; t.x = a; t.y = b;
    __hip_bfloat162 h = __float22bfloat162_rn(t);
    unsigned int u; __builtin_memcpy(&u, &h, 4); return u;
}

// ------------- kernel 1: precompute (weights packed in-block) -------------
__global__ __launch_bounds__(256) void precompute(
    const float* __restrict__ state,
    const float* __restrict__ Ws1, const float* __restrict__ bs1,
    const float* __restrict__ Ws2, const float* __restrict__ bs2,
    const float* __restrict__ Ws3, const float* __restrict__ bs3,
    const float* __restrict__ Wi1, const float* __restrict__ bi1,
    const float* __restrict__ Wi2, const float* __restrict__ bi2,
    const float* __restrict__ Wi3, const float* __restrict__ bi3,
    const float* __restrict__ phw, const float* __restrict__ Wc,
    const float* __restrict__ bc,  const float* __restrict__ aggr,
    float* __restrict__ ws, unsigned short* __restrict__ wsu) {
    const int tid = threadIdx.x;
    const int w = tid >> 6, t = tid & 63;
    const int i = blockIdx.x * 4 + w;

    __shared__ unsigned int wlds[PK_END];
    __shared__ float shh[4][32], shdh[4][32], sht1[4][64], sht2[4][64];
    __shared__ float shph[4];

    {
        const float2* s1 = (const float2*)Ws1;
        #pragma unroll
        for (int r = 0; r < 4; r++) { int e = tid + r * 256; int f = e >> 4, k2 = e & 15;
            float2 v = s1[e]; wlds[PK_W1 + k2 * 64 + f] = pk2(v.x, v.y); }
        const float2* s2 = (const float2*)Ws2;
        #pragma unroll
        for (int r = 0; r < 8; r++) { int e = tid + r * 256; int f = e >> 5, k2 = e & 31;
            float2 v = s2[e]; wlds[PK_W2 + k2 * 64 + f] = pk2(v.x, v.y); }
        const float2* s3 = (const float2*)Ws3;
        #pragma unroll
        for (int r = 0; r < 4; r++) { int e = tid + r * 256; int f = e >> 5, k2 = e & 31;
            float2 v = s3[e]; wlds[PK_W3 + k2 * 32 + f] = pk2(v.x, v.y); }
        const float2* si = (const float2*)Wi1;
        #pragma unroll
        for (int r = 0; r < 16; r++) { int e = tid + r * 256; int f = e >> 6, c2 = e & 63;
            float2 v = si[e]; wlds[PK_WI1 + c2 * 64 + f] = pk2(v.x, v.y); }
        const float2* sc = (const float2*)Wc;
        #pragma unroll
        for (int r = 0; r < 4; r++) { int e = tid + r * 256; int f = e >> 5, c2 = e & 31;
            float2 v = sc[e]; wlds[PK_WC + c2 * 32 + f] = pk2(v.x, v.y); }
    }
    if (blockIdx.x == 0) {
        #pragma unroll
        for (int r = 0; r < 16; r++) { int e = tid + r * 256; wsu[U_W2B + e] = f2bf(Wi2[e] * K2P); }
        #pragma unroll
        for (int r = 0; r < 8; r++)  { int e = tid + r * 256; wsu[U_W3B + e] = f2bf(Wi3[e]); }
        if (tid < HDIM) ws[WS_BI2 + tid] = bi2[tid] * K2P;
        if (tid < LDIM) ws[WS_BI3 + tid] = bi3[tid];
    }

    float sv = (t < 33) ? state[i * 33 + t] : 0.f;
    if (t < 32) shh[w][t] = sv;
    if (t == 32) shph[w] = sv;
    if (t == 33) ws[WS_AGG + i] = fast_sigmoid(aggr[i]);
    __syncthreads();

    {
        float s = bs1[t];
        const unsigned int* W = wlds + PK_W1;
        #pragma unroll
        for (int k2 = 0; k2 < 16; k2++) {
            unsigned int p = W[k2 * 64 + t];
            s = fmaf(blo(p), shh[w][2 * k2], s);
            s = fmaf(bhi(p), shh[w][2 * k2 + 1], s);
        }
        sht1[w][t] = fast_tanh(s);
    }
    __syncthreads();
    {
        float s = bs2[t];
        const unsigned int* W = wlds + PK_W2;
        #pragma unroll
        for (int k2 = 0; k2 < 32; k2++) {
            unsigned int p = W[k2 * 64 + t];
            s = fmaf(blo(p), sht1[w][2 * k2], s);
            s = fmaf(bhi(p), sht1[w][2 * k2 + 1], s);
        }
        sht2[w][t] = fast_tanh(s);
    }
    __syncthreads();
    if (t < 32) {
        float s = bs3[t];
        const unsigned int* W = wlds + PK_W3;
        #pragma unroll
        for (int k2 = 0; k2 < 32; k2++) {
            unsigned int p = W[k2 * 32 + t];
            s = fmaf(blo(p), sht2[w][2 * k2], s);
            s = fmaf(bhi(p), sht2[w][2 * k2 + 1], s);
        }
        ws[WS_SELF + i * 32 + t] = s;
        shdh[w][t] = s;
    }
    __syncthreads();
    {
        float sa = 0.f, sb = bi1[t];
        const unsigned int* W = wlds + PK_WI1;
        #pragma unroll
        for (int k2 = 0; k2 < 16; k2++) {
            float h0 = shh[w][2 * k2], h1 = shh[w][2 * k2 + 1];
            float d0 = shdh[w][2 * k2], d1 = shdh[w][2 * k2 + 1];
            unsigned int wa  = W[k2 * 64 + t];
            unsigned int wb  = W[(16 + k2) * 64 + t];
            unsigned int wa2 = W[(32 + k2) * 64 + t];
            unsigned int wb2 = W[(48 + k2) * 64 + t];
            sa = fmaf(blo(wa), h0, sa);  sa = fmaf(bhi(wa), h1, sa);
            sb = fmaf(blo(wb), h0, sb);  sb = fmaf(bhi(wb), h1, sb);
            sa = fmaf(blo(wa2), d0, sa); sa = fmaf(bhi(wa2), d1, sa);
            sb = fmaf(blo(wb2), d0, sb); sb = fmaf(bhi(wb2), d1, sb);
        }
        ws[WS_AA + i * 64 + t]  = sa * K2P;          // pre-scaled for tanh_pre
        wsu[U_BJB + i * 64 + t] = f2bf(sb * K2P);
    }
    if (t < 32) {
        float si = 0.f, sj = 0.f;
        const unsigned int* W = wlds + PK_WC;
        #pragma unroll
        for (int m2 = 0; m2 < 16; m2++) {
            float h0 = shh[w][2 * m2], h1 = shh[w][2 * m2 + 1];
            unsigned int wi = W[m2 * 32 + t];
            unsigned int wj = W[(16 + m2) * 32 + t];
            si = fmaf(blo(wi), h0, si); si = fmaf(bhi(wi), h1, si);
            sj = fmaf(blo(wj), h0, sj); sj = fmaf(bhi(wj), h1, sj);
        }
        ws[WS_CI + i * 32 + t] = (si + bc[t]) * K1N; // pre-scaled for rcp(1+exp2)
        float h = shh[w][t];
        wsu[U_HJB + i * 32 + t] = f2bf(h);
        float sc, cc;
        __sincosf(shph[w] * phw[t], &sc, &cc);
        uint2 jt; jt.x = pk2(h, sj * K1N); jt.y = pk2(cc, sc);
        *(uint2*)(wsu + U_JT + (i * 32 + t) * 4) = jt;
    }
}

// ------------- kernel 2: MFMA pairwise core (1 block per i) ---------------
// Verified optimum (r8): exp2-scaled tanh/sigmoid (trans pipe is quarter-rate
// ~4cy/inst — cheaper than any FMA poly), fac folded into epilogue FMA,
// per-wave double-buffered x2 tile with cross-tile stage-B deferral.
__global__ __launch_bounds__(256) void pair_kernel(
    const float* __restrict__ ws, const unsigned short* __restrict__ wsu,
    float* __restrict__ out) {
    const int i    = blockIdx.x;
    const int tid  = threadIdx.x;
    const int w    = tid >> 6;
    const int lane = tid & 63;
    const int q    = lane >> 4;
    const int m    = lane & 15;
    const int jw   = w * 16;
    const int sub  = lane & 3;

    __shared__ unsigned short W2ls[64 * 72];
    __shared__ unsigned short W3ls[32 * 72];
    __shared__ unsigned short x2ls[4 * 2 * 16 * 72];   // per-wave double buffer
    __shared__ float aLS[64];
    __shared__ float redT[4][32], redU[4][32], redV[4][32];
    __shared__ float sfw[4];

    // ---- setup ----
    if (tid < 64) aLS[tid] = ws[WS_AA + i * 64 + tid];
    {
        int row = tid >> 2, c = (tid & 3) * 16;
        const uint4* s2 = (const uint4*)(wsu + U_W2B + row * 64 + c);
        uint4 d0 = s2[0], d1 = s2[1];
        uint4* dd = (uint4*)(&W2ls[row * 72 + c]);
        dd[0] = d0; dd[1] = d1;
        if (row < 32) {
            const uint4* s3 = (const uint4*)(wsu + U_W3B + row * 64 + c);
            uint4 e0 = s3[0], e1 = s3[1];
            uint4* d3 = (uint4*)(&W3ls[row * 72 + c]);
            d3[0] = e0; d3[1] = e1;
        }
    }
    float hi8[8];
    {
        uint4 hv4 = *(const uint4*)(wsu + U_HJB + i * 32 + sub * 8);
        unsigned int hd[4] = {hv4.x, hv4.y, hv4.z, hv4.w};
        #pragma unroll
        for (int e = 0; e < 4; e++) { hi8[2 * e] = blo(hd[e]); hi8[2 * e + 1] = bhi(hd[e]); }
    }
    f32x4 b2q[4];              // pre-scaled bias slice for MFMA C-init
    #pragma unroll
    for (int nb = 0; nb < 4; nb++) {
        float4 bv = *(const float4*)(ws + WS_BI2 + nb * 16 + q * 4);
        b2q[nb][0] = bv.x; b2q[nb][1] = bv.y; b2q[nb][2] = bv.z; b2q[nb][3] = bv.w;
    }
    float hiv[2], cibv[2];
    #pragma unroll
    for (int lb = 0; lb < 2; lb++) {
        int l = lb * 16 + m;
        hiv[lb]  = bf2f(wsu[U_HJB + i * 32 + l]);
        cibv[lb] = ws[WS_CI + i * 32 + l];        // already has bc, pre-scaled
    }
    const float aggi = ws[WS_AGG + i];
    const float sub0 = (sub == 0) ? 1.0f : 0.0f;

    // ---- streaming pointers + tile-0 prefetch ----
    const unsigned short* hp = wsu + U_HJB + (jw + (lane >> 2)) * 32 + sub * 8;
    const unsigned short* bp = wsu + U_BJB + (jw + m) * 64 + q * 8;
    const unsigned short* jp = wsu + U_JT + ((jw + q * 4) * 32 + m) * 4;

    uint4 hvA = *(const uint4*)hp;
    uint4 b0A = *(const uint4*)bp;
    uint4 b1A = *(const uint4*)(bp + 32);
    uint4 hvB, b0B, b1B;
    __syncthreads();

    // persistent accumulators
    f32x4 accK[2];
    #pragma unroll
    for (int lb = 0; lb < 2; lb++) { accK[lb][0]=0.f; accK[lb][1]=0.f; accK[lb][2]=0.f; accK[lb][3]=0.f; }
    float aU[2] = {0.f, 0.f}, aV[2] = {0.f, 0.f};
    float sumfac = 0.f;

    unsigned short* xb0 = &x2ls[w * 2 * 1152];
    unsigned short* xb1 = xb0 + 1152;

    auto stageB = [&](const unsigned short* xb) {
        bf16x8 x2f[2];
        #pragma unroll
        for (int s = 0; s < 2; s++)
            x2f[s] = *(const bf16x8*)(&xb[m * 72 + s * 32 + q * 8]);
        #pragma unroll
        for (int lb = 0; lb < 2; lb++) {
            #pragma unroll
            for (int s = 0; s < 2; s++) {
                bf16x8 w3f = *(const bf16x8*)(&W3ls[(lb * 16 + m) * 72 + s * 32 + q * 8]);
                accK[lb] = __builtin_amdgcn_mfma_f32_16x16x32_bf16(x2f[s], w3f, accK[lb], 0, 0, 0);
            }
        }
    };

    auto body = [&](int T, uint4 hvc, uint4 b0c, uint4 b1c,
                    uint4& hvn, uint4& b0n, uint4& b1n,
                    unsigned short* xcur, const unsigned short* xprev) {
        // prefetch next tile's h/b
        hp += 2048; bp += 4096;
        hvn = *(const uint4*)hp;
        b0n = *(const uint4*)bp;
        b1n = *(const uint4*)(bp + 32);
        // jt loads for CURRENT tile (consumed at body end)
        uint2 jt[8];
        #pragma unroll
        for (int r = 0; r < 4; r++) {
            jt[r]     = *(const uint2*)(jp + r * 128);
            jt[4 + r] = *(const uint2*)(jp + 64 + r * 128);
        }
        jp += 8192;

        // deferred stage B for previous tile (LDS data a full body old)
        if (T > 0) stageB(xprev);

        // 1) fac (lane owns j = T*64 + jw + (lane>>2)); zeroed at j==i
        float facm;
        {
            unsigned int hd[4] = {hvc.x, hvc.y, hvc.z, hvc.w};
            float s = 0.f;
            #pragma unroll
            for (int e = 0; e < 4; e++) {
                float d0 = hi8[2 * e]     - blo(hd[e]);
                float d1 = hi8[2 * e + 1] - bhi(hd[e]);
                s = fmaf(d0, d0, s); s = fmaf(d1, d1, s);
            }
            s += __shfl_xor(s, 1); s += __shfl_xor(s, 2);
            int jj = T * 64 + jw + (lane >> 2);
            // rsq(s) == 1/(sqrt(s)+1e-6) to bf16 precision; s->0 clamps to 2 same as ref
            float facown = fminf(__builtin_amdgcn_rsqf(s), 2.0f) * aggi;
            facown = (jj == i) ? 0.0f : facown;
            sumfac = fmaf(sub0, facown, sumfac);
            facm = __shfl(facown, 4 * m);
        }
        const float fm2 = -2.0f * facm;

        // 2) x1 B-fragments: tanh via pre-scaled inputs (no multiplies)
        bf16x8 afr[2];
        {
            unsigned int bd[8] = {b0c.x, b0c.y, b0c.z, b0c.w, b1c.x, b1c.y, b1c.z, b1c.w};
            #pragma unroll
            for (int s = 0; s < 2; s++) {
                union { uint4 u4; bf16x8 v; } pkd;
                #pragma unroll
                for (int e = 0; e < 4; e++) {
                    const float* ab = &aLS[s * 32 + q * 8 + 2 * e];
                    float x0 = tanh_pre(ab[0] + blo(bd[s * 4 + e]));
                    float x1 = tanh_pre(ab[1] + bhi(bd[s * 4 + e]));
                    ((unsigned int*)&pkd.u4)[e] = pk2(x0, x1);
                }
                afr[s] = pkd.v;
            }
        }

        // 3) stage A: X2^T = Wi2' * X1^T, C-init = scaled bias
        f32x4 accA[4];
        #pragma unroll
        for (int nb = 0; nb < 4; nb++) {
            f32x4 acc = b2q[nb];
            #pragma unroll
            for (int s = 0; s < 2; s++) {
                bf16x8 w2f = *(const bf16x8*)(&W2ls[(nb * 16 + m) * 72 + s * 32 + q * 8]);
                acc = __builtin_amdgcn_mfma_f32_16x16x32_bf16(w2f, afr[s], acc, 0, 0, 0);
            }
            accA[nb] = acc;
        }
        // epilogue A: x2s = fac * tanh = fma(-2fac, rcp(exp2(acc)+1), fac)
        #pragma unroll
        for (int nb = 0; nb < 4; nb++) {
            float r0 = fast_rcp(__builtin_amdgcn_exp2f(accA[nb][0]) + 1.0f);
            float r1 = fast_rcp(__builtin_amdgcn_exp2f(accA[nb][1]) + 1.0f);
            float r2 = fast_rcp(__builtin_amdgcn_exp2f(accA[nb][2]) + 1.0f);
            float r3 = fast_rcp(__builtin_amdgcn_exp2f(accA[nb][3]) + 1.0f);
            float t0 = fmaf(fm2, r0, facm), t1 = fmaf(fm2, r1, facm);
            float t2 = fmaf(fm2, r2, facm), t3 = fmaf(fm2, r3, facm);
            uint2 pk; pk.x = pk2(t0, t1); pk.y = pk2(t2, t3);
            *(uint2*)(&xcur[m * 72 + nb * 16 + q * 4]) = pk;
        }

        // 5) stage C: quantum-term partials (pre-scaled sigmoid, diff=0 at j==i)
        #pragma unroll
        for (int lb = 0; lb < 2; lb++) {
            float u = 0.f, v = 0.f;
            #pragma unroll
            for (int r = 0; r < 4; r++) {
                uint2 jv = jt[lb * 4 + r];
                float hj = blo(jv.x), cj = bhi(jv.x);
                float pjc = blo(jv.y), pjs = bhi(jv.y);
                float coh = fast_rcp(1.0f + __builtin_amdgcn_exp2f(cibv[lb] + cj));
                float cd  = coh * (hiv[lb] - hj);
                u = fmaf(cd, pjc, u);
                v = fmaf(cd, pjs, v);
            }
            aU[lb] += u; aV[lb] += v;
        }
    };

    #pragma unroll 1
    for (int T = 0; T < 16; T += 2) {
        body(T,     hvA, b0A, b1A, hvB, b0B, b1B, xb0, xb1);
        body(T + 1, hvB, b0B, b1B, hvA, b0A, b1A, xb1, xb0);
    }
    stageB(xb1);   // tile 15

    // ---- final reductions ----
    float T1[2];
    #pragma unroll
    for (int lb = 0; lb < 2; lb++) {
        T1[lb] = (accK[lb][0] + accK[lb][1]) + (accK[lb][2] + accK[lb][3]);
        T1[lb] += __shfl_xor(T1[lb], 16); T1[lb] += __shfl_xor(T1[lb], 32);
        aU[lb] += __shfl_xor(aU[lb], 16); aU[lb] += __shfl_xor(aU[lb], 32);
        aV[lb] += __shfl_xor(aV[lb], 16); aV[lb] += __shfl_xor(aV[lb], 32);
    }
    sumfac += __shfl_xor(sumfac, 1);  sumfac += __shfl_xor(sumfac, 2);
    sumfac += __shfl_xor(sumfac, 4);  sumfac += __shfl_xor(sumfac, 8);
    sumfac += __shfl_xor(sumfac, 16); sumfac += __shfl_xor(sumfac, 32);
    if (lane < 16) {
        redT[w][m] = T1[0];      redT[w][16 + m] = T1[1];
        redU[w][m] = aU[0];      redU[w][16 + m] = aU[1];
        redV[w][m] = aV[0];      redV[w][16 + m] = aV[1];
    }
    if (lane == 0) sfw[w] = sumfac;
    __syncthreads();
    if (tid < 32) {
        int l = tid;
        float t1 = (redT[0][l] + redT[1][l]) + (redT[2][l] + redT[3][l]);
        float uu = (redU[0][l] + redU[1][l]) + (redU[2][l] + redU[3][l]);
        float vv = (redV[0][l] + redV[1][l]) + (redV[2][l] + redV[3][l]);
        float sf = (sfw[0] + sfw[1]) + (sfw[2] + sfw[3]);
        uint2 jti = *(const uint2*)(wsu + U_JT + (i * 32 + l) * 4);
        float pic = blo(jti.y), pis = bhi(jti.y);
        float isum = t1 + sf * ws[WS_BI3 + l] - (pic * uu + pis * vv);
        out[i * 33 + l] = 0.5f * ws[WS_SELF + i * 32 + l] + 0.3f * isum;
        redT[0][l] = fabsf(isum);
    }
    __syncthreads();
    if (tid == 0) {
        float s = 0.f;
        #pragma unroll
        for (int l = 0; l < 32; l++) s += redT[0][l];
        out[i * 33 + 32] = 0.1f + 0.05f * s;
    }
}

extern "C" void kernel_launch(void* const* d_in, const int* in_sizes, int n_in,
                              void* d_out, int out_size, void* d_ws, size_t ws_size,
                              hipStream_t stream) {
    const float* state   = (const float*)d_in[0];
    const float* Ws1     = (const float*)d_in[1];
    const float* bs1     = (const float*)d_in[2];
    const float* Ws2     = (const float*)d_in[3];
    const float* bs2     = (const float*)d_in[4];
    const float* Ws3     = (const float*)d_in[5];
    const float* bs3     = (const float*)d_in[6];
    const float* Wi1     = (const float*)d_in[7];
    const float* bi1     = (const float*)d_in[8];
    const float* Wi2     = (const float*)d_in[9];
    const float* bi2     = (const float*)d_in[10];
    const float* Wi3     = (const float*)d_in[11];
    const float* bi3     = (const float*)d_in[12];
    const float* phase_w = (const float*)d_in[13];
    const float* Wc      = (const float*)d_in[14];
    const float* bc      = (const float*)d_in[15];
    const float* aggr    = (const float*)d_in[16];

    float* ws = (float*)d_ws;
    unsigned short* wsu = (unsigned short*)(ws + WS_FEND);
    float* out = (float*)d_out;

    precompute<<<256, 256, 0, stream>>>(state, Ws1, bs1, Ws2, bs2, Ws3, bs3,
                                        Wi1, bi1, Wi2, bi2, Wi3, bi3,
                                        phase_w, Wc, bc, aggr, ws, wsu);
    pair_kernel<<<NN, 256, 0, stream>>>(ws, wsu, out);
}